// Round 7
// baseline (1217.511 us; speedup 1.0000x reference)
//
#include <hip/hip_runtime.h>
#include <math.h>

#define NN   100000
#define EE   800000
#define RR   6
#define BB   1000
#define HH   128
#define MM   (RR*NN)
#define NBPR ((NN + 255) >> 8)
#define NBK  (RR * NBPR)
#define CH   4096

static inline int ceil_div(int a, int b){ return (a+b-1)/b; }

typedef __attribute__((ext_vector_type(8))) short bf16x8;
typedef __attribute__((ext_vector_type(4))) short bf16x4;
typedef __attribute__((ext_vector_type(4))) float f32x4;

__device__ __forceinline__ unsigned fenc(float f){
  unsigned u = __float_as_uint(f);
  return (u & 0x80000000u) ? ~u : (u | 0x80000000u);
}
__device__ __forceinline__ float fdec(unsigned u){
  return __uint_as_float((u & 0x80000000u) ? (u & 0x7fffffffu) : ~u);
}
__device__ __forceinline__ unsigned short f2bf(float f){
  unsigned u = __float_as_uint(f);
  return (unsigned short)((u + 0x7fffu + ((u >> 16) & 1u)) >> 16);
}
__device__ __forceinline__ float bf2f(unsigned short h){
  return __uint_as_float(((unsigned)h) << 16);
}

// ================= bucketed CSR build (proven) =================
__global__ void k_bcount(const int* __restrict__ edges, int* __restrict__ bcnt)
{
  __shared__ int hist[NBPR];
  int t = threadIdx.x;
  const int nch = (EE + CH - 1) / CH;
  int r = blockIdx.x / nch, c = blockIdx.x - r*nch;
  for (int i = t; i < NBPR; i += 256) hist[i] = 0;
  __syncthreads();
  const int* dptr = edges + (size_t)r*2*EE + EE;
  int e0 = c*CH, e1 = min(EE, e0 + CH);
  for (int i = e0 + t; i < e1; i += 256)
    atomicAdd(&hist[dptr[i] >> 8], 1);
  __syncthreads();
  for (int i = t; i < NBPR; i += 256) {
    int h = hist[i];
    if (h) atomicAdd(&bcnt[r*NBPR + i], h);
  }
}

__global__ void k_bscan(const int* __restrict__ bcnt, int* __restrict__ boff,
                        int* __restrict__ off)
{
  __shared__ int sh[256];
  int t = threadIdx.x;
  int carry = 0;
  for (int c = 0; c < NBK; c += 256) {
    int idx = c + t;
    int v = (idx < NBK) ? bcnt[idx] : 0;
    sh[t] = v;
    __syncthreads();
    for (int o = 1; o < 256; o <<= 1) {
      int add = (t >= o) ? sh[t-o] : 0;
      __syncthreads();
      sh[t] += add;
      __syncthreads();
    }
    int incl = sh[t];
    int tot  = sh[255];
    if (idx < NBK) boff[idx] = carry + incl - v;
    __syncthreads();
    carry += tot;
  }
  if (t == 0) { boff[NBK] = carry; off[MM] = carry; }
}

__global__ void k_binscatter(const int* __restrict__ edges, int* __restrict__ bcur,
                             unsigned* __restrict__ ebkt)
{
  __shared__ int hist[NBPR];
  __shared__ int base[NBPR];
  int t = threadIdx.x;
  const int nch = (EE + CH - 1) / CH;
  int r = blockIdx.x / nch, c = blockIdx.x - r*nch;
  for (int i = t; i < NBPR; i += 256) hist[i] = 0;
  __syncthreads();
  const int* sptr = edges + (size_t)r*2*EE;
  const int* dptr = sptr + EE;
  int e0 = c*CH, e1 = min(EE, e0 + CH);
  for (int i = e0 + t; i < e1; i += 256)
    atomicAdd(&hist[dptr[i] >> 8], 1);
  __syncthreads();
  for (int i = t; i < NBPR; i += 256) {
    int h = hist[i];
    base[i] = h ? atomicAdd(&bcur[r*NBPR + i], h) : 0;
    hist[i] = 0;
  }
  __syncthreads();
  for (int i = e0 + t; i < e1; i += 256) {
    int dst = dptr[i];
    int b = dst >> 8;
    int slot = base[b] + atomicAdd(&hist[b], 1);
    ebkt[slot] = ((unsigned)sptr[i] << 8) | (unsigned)(dst & 255);
  }
}

__global__ void k_bbuild(const unsigned* __restrict__ ebkt, const int* __restrict__ boff,
                         int* __restrict__ off, int* __restrict__ elist)
{
  __shared__ int cnt[256];
  __shared__ int sc[256];
  __shared__ int cur[256];
  int t = threadIdx.x;
  int bb = blockIdx.x;
  int e0 = boff[bb], e1 = boff[bb+1];
  cnt[t] = 0;
  __syncthreads();
  for (int i = e0 + t; i < e1; i += 256)
    atomicAdd(&cnt[ebkt[i] & 255u], 1);
  __syncthreads();
  sc[t] = cnt[t];
  __syncthreads();
  for (int o = 1; o < 256; o <<= 1) {
    int add = (t >= o) ? sc[t-o] : 0;
    __syncthreads();
    sc[t] += add;
    __syncthreads();
  }
  int excl = sc[t] - cnt[t];
  int r = bb / NBPR, b = bb - r*NBPR;
  int dst = b*256 + t;
  if (dst < NN) off[r*NN + dst] = e0 + excl;
  cur[t] = e0 + excl;
  __syncthreads();
  for (int i = e0 + t; i < e1; i += 256) {
    unsigned w = ebkt[i];
    int slot = atomicAdd(&cur[w & 255u], 1);
    elist[slot] = (int)(w >> 8);
  }
}

// ================= feature prep (bf16 hi/lo planes, K padded 21->32) =================
__global__ void k_featprep(const float* __restrict__ x_all, const float* __restrict__ pos_table,
                           short* __restrict__ x0h, short* __restrict__ x0l)
{
  int gid = blockIdx.x*256 + threadIdx.x;
  if (gid >= NN*32) return;
  int nidx = gid >> 5, c = gid & 31;
  float v = 0.f;
  if (c < 13) {
    int scl = (c < 5) ? c : c + 1;
    v = x_all[nidx*14 + scl];
  } else if (c < 21) {
    int pi = (int)x_all[nidx*14 + 5];
    pi = pi < 0 ? 0 : (pi > 23 ? 23 : pi);
    v = pos_table[pi*8 + (c - 13)];
  }
  unsigned short h = f2bf(v);
  unsigned short l = f2bf(v - bf2f(h));
  x0h[gid] = (short)h;
  x0l[gid] = (short)l;
}

// ================= weight prep: W[r][k][128] f32 -> Wt[r][out=128][KP] bf16 hi/lo ======
template<int KP>
__global__ void k_wprep(const float* __restrict__ W, int K,
                        short* __restrict__ Wh, short* __restrict__ Wl)
{
  int gid = blockIdx.x*256 + threadIdx.x;
  if (gid >= RR*128*KP) return;
  int r = gid / (128*KP);
  int rem = gid - r*(128*KP);
  int nn = rem / KP, k = rem - nn*KP;
  float v = (k < K) ? W[((size_t)r*K + k)*128 + nn] : 0.f;
  unsigned short h = f2bf(v);
  unsigned short l = f2bf(v - bf2f(h));
  Wh[gid] = (short)h;
  Wl[gid] = (short)l;
}

// ================= wa: precompute W_r @ a  (for z = x . (W a)) =================
template<int KP>
__global__ void k_wa(const float* __restrict__ W, const float* __restrict__ as,
                     const float* __restrict__ ad, int K, float* __restrict__ wa)
{
  int idx = blockIdx.x*256 + threadIdx.x;
  if (idx >= 12*KP) return;
  int rr = idx / KP, k = idx - rr*KP;
  int r = (rr < 6) ? rr : rr - 6;
  const float* a = ((rr < 6) ? as : ad) + (size_t)r*HH;
  float s = 0.f;
  if (k < K) {
    const float* wrow = W + ((size_t)r*K + k)*128;
    #pragma unroll 8
    for (int h = 0; h < 128; ++h) s = fmaf(wrow[h], a[h], s);
  }
  wa[idx] = s;
}

// ================= zsd: z-scores per node per relation ====================
__global__ void k_zsd32(const short* __restrict__ xh, const short* __restrict__ xl,
                        const float* __restrict__ wa, float* __restrict__ zsd, int n)
{
  __shared__ float w[12*32];
  int tid = threadIdx.x;
  for (int i = tid; i < 12*32; i += 256) w[i] = wa[i];
  __syncthreads();
  int g = blockIdx.x*256 + tid;
  if (g >= n) return;
  float v[32];
  #pragma unroll
  for (int c = 0; c < 4; ++c) {
    uint4 vh = *(const uint4*)(xh + (size_t)g*32 + c*8);
    uint4 vl = *(const uint4*)(xl + (size_t)g*32 + c*8);
    const unsigned short* hp = (const unsigned short*)&vh;
    const unsigned short* lp = (const unsigned short*)&vl;
    #pragma unroll
    for (int j = 0; j < 8; ++j) v[c*8+j] = bf2f(hp[j]) + bf2f(lp[j]);
  }
  #pragma unroll
  for (int rr = 0; rr < 12; ++rr) {
    float d = 0.f;
    #pragma unroll
    for (int k = 0; k < 32; ++k) d = fmaf(v[k], w[rr*32+k], d);
    zsd[(size_t)rr*n + g] = d;
  }
}

__global__ void k_zsd128(const unsigned short* __restrict__ xh, const unsigned short* __restrict__ xl,
                         const float* __restrict__ wa, float* __restrict__ zsd, int n)
{
  __shared__ float w[12*128];
  int tid = threadIdx.x;
  for (int i = tid; i < 12*128; i += 256) w[i] = wa[i];
  __syncthreads();
  int gid = blockIdx.x*256 + tid;
  int g = gid >> 4, l = tid & 15;
  if (g >= n) return;
  uint4 vh = *(const uint4*)(xh + (size_t)g*128 + l*8);
  uint4 vl = *(const uint4*)(xl + (size_t)g*128 + l*8);
  const unsigned short* hp = (const unsigned short*)&vh;
  const unsigned short* lp = (const unsigned short*)&vl;
  float v[8];
  #pragma unroll
  for (int j = 0; j < 8; ++j) v[j] = bf2f(hp[j]) + bf2f(lp[j]);
  float dot[12];
  #pragma unroll
  for (int rr = 0; rr < 12; ++rr) {
    float p = 0.f;
    #pragma unroll
    for (int j = 0; j < 8; ++j) p = fmaf(v[j], w[rr*128 + l*8 + j], p);
    p += __shfl_xor(p, 1); p += __shfl_xor(p, 2);
    p += __shfl_xor(p, 4); p += __shfl_xor(p, 8);
    dot[rr] = p;
  }
  if (l < 12) zsd[(size_t)l*n + g] = dot[l];
}

// ================= fused aggregate + concat-GEMM + epilogue ====================
// A fragments from LDS (swizzled); W fragments straight from global (L2-resident).
__device__ __forceinline__ bf16x8 ldfrag_(const short* p, int row, int kb, int KP_, int smask)
{
  int xr = row & smask;
  int s0 = (((kb)      >> 3) ^ xr) * 8 + (kb & 7);
  int s1 = (((kb + 16) >> 3) ^ xr) * 8 + (kb & 7);
  bf16x4 a = *(const bf16x4*)(p + (size_t)row*KP_ + s0);
  bf16x4 b = *(const bf16x4*)(p + (size_t)row*KP_ + s1);
  return __builtin_shufflevector(a, b, 0,1,2,3,4,5,6,7);
}

__device__ __forceinline__ bf16x8 ldfragG(const short* __restrict__ p, int row, int kb, int KP_)
{
  bf16x4 a = *(const bf16x4*)(p + (size_t)row*KP_ + kb);
  bf16x4 b = *(const bf16x4*)(p + (size_t)row*KP_ + kb + 16);
  return __builtin_shufflevector(a, b, 0,1,2,3,4,5,6,7);
}

// FIN=1: write h1 bf16 hi/lo planes.  FIN=2: write f32 + fused pool score.
template<int KPR, int FIN>
__global__ __launch_bounds__(256, 5)
void k_fused(const unsigned short* __restrict__ tab,   // [n][KPR] bf16 gather table
             const float* __restrict__ zsd,            // [12][n]
             const int* __restrict__ elist,
             const int* __restrict__ off,              // [MM+1]
             const short* __restrict__ Wh, const short* __restrict__ Wl,  // [6][128][KPR]
             const float* __restrict__ bsv,
             const float* __restrict__ nw, const float* __restrict__ nb,
             unsigned short* __restrict__ Yh, unsigned short* __restrict__ Yl,
             float* __restrict__ Yf, const float* __restrict__ q,
             const int* __restrict__ batch, float* __restrict__ scores,
             unsigned* __restrict__ bmax, int n)
{
  constexpr int SLOTS = KPR/8;
  constexpr int SMASK = (SLOTS >= 8) ? 7 : (SLOTS-1);
  constexpr int ASH = 32*KPR;           // shorts per A plane
  constexpr int UB0 = 2*ASH*2;          // Ah + Al bytes
  constexpr int UBYTES = (UB0 > 32*136*4) ? UB0 : 32*136*4;
  __shared__ __align__(16) char ldsraw[UBYTES];
  short* Ah = (short*)ldsraw;
  short* Al = Ah + ASH;

  int tid = threadIdx.x;
  int gi = tid >> 4;        // 16 groups
  int l  = tid & 15;
  int gb = tid & 48;        // group base lane within wave
  int r0 = blockIdx.x * 32;

  int wid = tid >> 6, lane = tid & 63;
  int lr = lane & 15, lg = lane >> 4;
  int rt = wid >> 1;
  int c0 = (wid & 1) * 4;
  int arow = rt*16 + lr;
  f32x4 acct[4] = {{0,0,0,0},{0,0,0,0},{0,0,0,0},{0,0,0,0}};

  for (int rel = 0; rel < RR; ++rel) {
    const short* Whr = Wh + (size_t)rel*128*KPR;
    const short* Wlr = Wl + (size_t)rel*128*KPR;
    const float* zsr = zsd + (size_t)rel*n;
    const float* zdr = zsd + (size_t)(6+rel)*n;

    // ---- (a) aggregate 2 rows per 16-lane group into A hi/lo tiles ----
    #pragma unroll
    for (int rr = 0; rr < 2; ++rr) {
      int row = gi + rr*16;
      int g = r0 + row;
      float acc[8] = {0,0,0,0,0,0,0,0};
      float inv = 0.f;
      int o0 = off[(size_t)rel*NN + g];
      int deg = off[(size_t)rel*NN + g + 1] - o0;
      if (deg > 0) {
        float zdd = zdr[g];
        // online softmax: single pass for (max, sum)
        float m = -3.4e38f, es = 0.f;
        for (int i = l; i < deg; i += 16) {
          float z = zsr[elist[o0+i]] + zdd;
          z = (z > 0.f) ? z : 0.2f*z;
          float mn = fmaxf(m, z);
          es = es*__expf(m - mn) + __expf(z - mn);
          m = mn;
        }
        #pragma unroll
        for (int o = 1; o <= 8; o <<= 1) {
          float mo = __shfl_xor(m, o), eo = __shfl_xor(es, o);
          float mn = fmaxf(m, mo);
          es = es*__expf(m - mn) + eo*__expf(mo - mn);
          m = mn;
        }
        inv = 1.f / es;
        if (KPR == 128) {
          for (int base = 0; base < deg; base += 16) {
            int i = base + l;
            float ew = 0.f; int s = 0;
            if (i < deg) {
              s = elist[o0+i];
              float z = zsr[s] + zdd;
              z = (z > 0.f) ? z : 0.2f*z;
              ew = __expf(z - m);
            }
            int cnt = min(16, deg - base);
            for (int t = 0; t < cnt; ++t) {
              float w = __shfl(ew, gb + t);
              int ss = __shfl(s, gb + t);
              uint4 v = *(const uint4*)(tab + (size_t)ss*KPR + l*8);
              acc[0] = fmaf(w, __uint_as_float(v.x << 16),         acc[0]);
              acc[1] = fmaf(w, __uint_as_float(v.x & 0xffff0000u), acc[1]);
              acc[2] = fmaf(w, __uint_as_float(v.y << 16),         acc[2]);
              acc[3] = fmaf(w, __uint_as_float(v.y & 0xffff0000u), acc[3]);
              acc[4] = fmaf(w, __uint_as_float(v.z << 16),         acc[4]);
              acc[5] = fmaf(w, __uint_as_float(v.z & 0xffff0000u), acc[5]);
              acc[6] = fmaf(w, __uint_as_float(v.w << 16),         acc[6]);
              acc[7] = fmaf(w, __uint_as_float(v.w & 0xffff0000u), acc[7]);
            }
          }
        } else {  // KPR==32: 4 edges per iter, 4 lanes per edge
          int sub = l >> 2, ch = l & 3;
          for (int base = 0; base < deg; base += 4) {
            int i = base + sub;
            float ew = 0.f; int ss = 0;
            if (i < deg) {
              ss = elist[o0+i];
              float z = zsr[ss] + zdd;
              z = (z > 0.f) ? z : 0.2f*z;
              ew = __expf(z - m);
            }
            uint4 v = *(const uint4*)(tab + (size_t)ss*KPR + ch*8);
            acc[0] = fmaf(ew, __uint_as_float(v.x << 16),         acc[0]);
            acc[1] = fmaf(ew, __uint_as_float(v.x & 0xffff0000u), acc[1]);
            acc[2] = fmaf(ew, __uint_as_float(v.y << 16),         acc[2]);
            acc[3] = fmaf(ew, __uint_as_float(v.y & 0xffff0000u), acc[3]);
            acc[4] = fmaf(ew, __uint_as_float(v.z << 16),         acc[4]);
            acc[5] = fmaf(ew, __uint_as_float(v.z & 0xffff0000u), acc[5]);
            acc[6] = fmaf(ew, __uint_as_float(v.w << 16),         acc[6]);
            acc[7] = fmaf(ew, __uint_as_float(v.w & 0xffff0000u), acc[7]);
          }
          #pragma unroll
          for (int j = 0; j < 8; ++j) {
            acc[j] += __shfl_xor(acc[j], 4);
            acc[j] += __shfl_xor(acc[j], 8);
          }
        }
      }
      // write A row (hi/lo split of f32 aggregate)
      if (KPR == 128 || l < 4) {
        int slot = l;
        uint4 ph, pl;
        unsigned* php = (unsigned*)&ph; unsigned* plp = (unsigned*)&pl;
        #pragma unroll
        for (int j2 = 0; j2 < 4; ++j2) {
          float a0 = acc[2*j2]   * inv;
          float a1 = acc[2*j2+1] * inv;
          unsigned short h0 = f2bf(a0), h1 = f2bf(a1);
          php[j2] = ((unsigned)h1 << 16) | h0;
          plp[j2] = ((unsigned)f2bf(a1 - bf2f(h1)) << 16) | f2bf(a0 - bf2f(h0));
        }
        int dsl = ((slot ^ (row & SMASK))) * 8;
        *(uint4*)(Ah + row*KPR + dsl) = ph;
        *(uint4*)(Al + row*KPR + dsl) = pl;
      }
    }
    __syncthreads();
    // ---- (b) MFMA: A from LDS, W fragments from global (single pass, 3 MFMAs) ----
    #pragma unroll
    for (int kc = 0; kc < KPR/32; ++kc) {
      int kb = kc*32 + 4*lg;
      bf16x8 ah = ldfrag_(Ah, arow, kb, KPR, SMASK);
      bf16x8 al = ldfrag_(Al, arow, kb, KPR, SMASK);
      #pragma unroll
      for (int t = 0; t < 4; ++t) {
        int wrow = (c0 + t)*16 + lr;
        bf16x8 whf = ldfragG(Whr, wrow, kb, KPR);
        bf16x8 wlf = ldfragG(Wlr, wrow, kb, KPR);
        acct[t] = __builtin_amdgcn_mfma_f32_16x16x32_bf16(ah, whf, acct[t], 0, 0, 0);
        acct[t] = __builtin_amdgcn_mfma_f32_16x16x32_bf16(al, whf, acct[t], 0, 0, 0);
        acct[t] = __builtin_amdgcn_mfma_f32_16x16x32_bf16(ah, wlf, acct[t], 0, 0, 0);
      }
    }
    __syncthreads();
  }

  // ---- epilogue: bias + gelu -> Cs, then per-row LN ----
  float* Cs = (float*)ldsraw;   // [32][136]
  #pragma unroll
  for (int t = 0; t < 4; ++t)
    #pragma unroll
    for (int v = 0; v < 4; ++v) {
      int row = rt*16 + lg*4 + v;
      int col = (c0 + t)*16 + lr;
      float x = acct[t][v] + bsv[col];
      Cs[row*136 + col] = 0.5f*x*(1.f + erff(x*0.70710678118654752f));
    }
  __syncthreads();

  {
    int r = tid >> 3, sg = tid & 7;
    float vals[16];
    float s = 0.f;
    #pragma unroll
    for (int i = 0; i < 16; ++i) { vals[i] = Cs[r*136 + sg*16 + i]; s += vals[i]; }
    s += __shfl_xor(s, 1); s += __shfl_xor(s, 2); s += __shfl_xor(s, 4);
    float mu = s * (1.f/128.f);
    float var = 0.f;
    #pragma unroll
    for (int i = 0; i < 16; ++i) { vals[i] -= mu; var += vals[i]*vals[i]; }
    var += __shfl_xor(var, 1); var += __shfl_xor(var, 2); var += __shfl_xor(var, 4);
    float inv = 1.f / sqrtf(var*(1.f/128.f) + 1e-5f);
    int g = r0 + r;
    if (FIN == 1) {
      uint4 ph0, ph1, pl0, pl1;
      unsigned* php0 = (unsigned*)&ph0; unsigned* php1 = (unsigned*)&ph1;
      unsigned* plp0 = (unsigned*)&pl0; unsigned* plp1 = (unsigned*)&pl1;
      #pragma unroll
      for (int j2 = 0; j2 < 8; ++j2) {
        int c = sg*16 + 2*j2;
        float y0 = vals[2*j2]  *inv*nw[c]   + nb[c];
        float y1 = vals[2*j2+1]*inv*nw[c+1] + nb[c+1];
        unsigned short h0 = f2bf(y0), h1 = f2bf(y1);
        unsigned hw = ((unsigned)h1 << 16) | h0;
        unsigned lw = ((unsigned)f2bf(y1 - bf2f(h1)) << 16) | f2bf(y0 - bf2f(h0));
        if (j2 < 4) { php0[j2] = hw; plp0[j2] = lw; }
        else        { php1[j2-4] = hw; plp1[j2-4] = lw; }
      }
      *(uint4*)(Yh + (size_t)g*128 + sg*16)     = ph0;
      *(uint4*)(Yh + (size_t)g*128 + sg*16 + 8) = ph1;
      *(uint4*)(Yl + (size_t)g*128 + sg*16)     = pl0;
      *(uint4*)(Yl + (size_t)g*128 + sg*16 + 8) = pl1;
    } else {
      float sc = 0.f;
      #pragma unroll
      for (int j2 = 0; j2 < 4; ++j2) {
        float4 o;
        int c = sg*16 + j2*4;
        o.x = vals[j2*4+0]*inv*nw[c+0] + nb[c+0];
        o.y = vals[j2*4+1]*inv*nw[c+1] + nb[c+1];
        o.z = vals[j2*4+2]*inv*nw[c+2] + nb[c+2];
        o.w = vals[j2*4+3]*inv*nw[c+3] + nb[c+3];
        *(float4*)(Yf + (size_t)g*128 + c) = o;
        sc += o.x*q[c] + o.y*q[c+1] + o.z*q[c+2] + o.w*q[c+3];
      }
      sc += __shfl_xor(sc, 1); sc += __shfl_xor(sc, 2); sc += __shfl_xor(sc, 4);
      if (sg == 0) {
        scores[g] = sc;
        atomicMax(&bmax[batch[g]], fenc(sc));
      }
    }
  }
}

// ================= bias-sum =================
__global__ void k_bsum(const float* __restrict__ b, float* __restrict__ bs)
{
  int t = threadIdx.x;
  float s = 0.f;
  #pragma unroll
  for (int r = 0; r < RR; ++r) s += b[r*HH + t];
  bs[t] = s;
}

// ================= pooling =================
__global__ void k_segbounds(const int* __restrict__ batch, int* __restrict__ segst,
                            int n, int numB)
{
  int b = blockIdx.x*256 + threadIdx.x;
  if (b > numB) return;
  int lo = 0, hi = n;
  while (lo < hi) { int mid = (lo+hi) >> 1; if (batch[mid] < b) lo = mid+1; else hi = mid; }
  segst[b] = lo;
}

__global__ void k_pool(const float* __restrict__ X, const float* __restrict__ scores,
                       const int* __restrict__ segst, const unsigned* __restrict__ bmax,
                       float* __restrict__ pool, int numB)
{
  int b = blockIdx.x;
  int t = threadIdx.x;
  int s0 = segst[b], s1 = segst[b+1];
  float m = fdec(bmax[b]);
  float acc0 = 0.f, acc1 = 0.f, esum = 0.f;
  int i = s0;
  for (; i + 1 < s1; i += 2) {
    float e0 = __expf(scores[i] - m);
    float e1 = __expf(scores[i+1] - m);
    esum += e0 + e1;
    acc0 = fmaf(e0, X[(size_t)i*128 + t], acc0);
    acc1 = fmaf(e1, X[(size_t)(i+1)*128 + t], acc1);
  }
  if (i < s1) {
    float e0 = __expf(scores[i] - m);
    esum += e0;
    acc0 = fmaf(e0, X[(size_t)i*128 + t], acc0);
  }
  float inv = (s1 > s0) ? 1.f/esum : 0.f;
  pool[(size_t)b*128 + t] = (acc0 + acc1) * inv;
}

__global__ void k_outgemm(const float* __restrict__ pool, const float* __restrict__ projW,
                          const float* __restrict__ projb, float* __restrict__ out, int numB)
{
  int b = blockIdx.x;
  int j = threadIdx.x;
  __shared__ float p[128];
  p[j] = pool[(size_t)b*128 + j];
  __syncthreads();
  float acc = projb[j];
  #pragma unroll 16
  for (int k = 0; k < 128; ++k) acc = fmaf(p[k], projW[(size_t)k*128 + j], acc);
  out[(size_t)b*128 + j] = acc;
}

// ================= launcher =================
extern "C" void kernel_launch(void* const* d_in, const int* in_sizes, int n_in,
                              void* d_out, int out_size, void* d_ws, size_t ws_size,
                              hipStream_t stream)
{
  const float* x_all = (const float*)d_in[0];
  const int*   edges = (const int*)d_in[1];
  const int*   batch = (const int*)d_in[2];
  const float* pos_table = (const float*)d_in[3];
  const float* W1  = (const float*)d_in[4];
  const float* as1 = (const float*)d_in[5];
  const float* ad1 = (const float*)d_in[6];
  const float* b1  = (const float*)d_in[7];
  const float* W2  = (const float*)d_in[8];
  const float* as2 = (const float*)d_in[9];
  const float* ad2 = (const float*)d_in[10];
  const float* b2  = (const float*)d_in[11];
  const float* n1w = (const float*)d_in[12];
  const float* n1b = (const float*)d_in[13];
  const float* n2w = (const float*)d_in[14];
  const float* n2b = (const float*)d_in[15];
  const float* query = (const float*)d_in[16];
  const float* projW = (const float*)d_in[17];
  const float* projb = (const float*)d_in[18];
  float* out = (float*)d_out;
  (void)in_sizes; (void)n_in; (void)out_size; (void)ws_size;

  char* p = (char*)d_ws;
  auto alloc = [&](size_t b){ void* r = (void*)p; p += (b + 255) & ~(size_t)255; return r; };
  int*   off   = (int*)alloc((size_t)(MM+1)*sizeof(int));
  int*   elist = (int*)alloc((size_t)RR*EE*sizeof(int));
  int*   bcnt  = (int*)alloc((size_t)NBK*sizeof(int));
  int*   boff  = (int*)alloc((size_t)(NBK+1)*sizeof(int));
  int*   bcur  = (int*)alloc((size_t)NBK*sizeof(int));
  short* wtH   = (short*)alloc((size_t)RR*128*128*sizeof(short));
  short* wtL   = (short*)alloc((size_t)RR*128*128*sizeof(short));
  float* wa    = (float*)alloc((size_t)12*128*sizeof(float));
  float* zsd   = (float*)alloc((size_t)12*NN*sizeof(float));
  float* bsv   = (float*)alloc(128*sizeof(float));
  int*   segst = (int*)alloc((size_t)(BB+1)*sizeof(int));
  unsigned* bmax = (unsigned*)alloc((size_t)BB*sizeof(unsigned));
  float* pool  = (float*)alloc((size_t)BB*HH*sizeof(float));
  float* scrs  = (float*)alloc((size_t)NN*sizeof(float));
  short* x0h   = (short*)alloc((size_t)NN*32*sizeof(short));
  short* x0l   = (short*)alloc((size_t)NN*32*sizeof(short));
  unsigned short* h1h = (unsigned short*)alloc((size_t)NN*128*sizeof(short));
  unsigned short* h1l = (unsigned short*)alloc((size_t)NN*128*sizeof(short));
  float* h2    = (float*)alloc((size_t)NN*128*sizeof(float));
  unsigned* ebkt = (unsigned*)h2;   // transient: dead after k_bbuild, before h2 written

  // --- CSR build ---
  const int nch = (EE + CH - 1) / CH;
  hipMemsetAsync(bcnt, 0, (size_t)NBK*sizeof(int), stream);
  k_bcount<<<RR*nch,256,0,stream>>>(edges, bcnt);
  k_bscan<<<1,256,0,stream>>>(bcnt, boff, off);
  hipMemcpyAsync(bcur, boff, (size_t)NBK*sizeof(int), hipMemcpyDeviceToDevice, stream);
  k_binscatter<<<RR*nch,256,0,stream>>>(edges, bcur, ebkt);
  k_bbuild<<<NBK,256,0,stream>>>(ebkt, boff, off, elist);

  // --- prep ---
  k_featprep<<<ceil_div(NN*32,256),256,0,stream>>>(x_all, pos_table, x0h, x0l);
  k_segbounds<<<ceil_div(BB+1,256),256,0,stream>>>(batch, segst, NN, BB);
  hipMemsetAsync(bmax, 0, (size_t)BB*sizeof(unsigned), stream);

  // --- layer 1 (fused agg-then-project) ---
  k_wa<32><<<ceil_div(12*32,256),256,0,stream>>>(W1, as1, ad1, 21, wa);
  k_zsd32<<<ceil_div(NN,256),256,0,stream>>>(x0h, x0l, wa, zsd, NN);
  k_wprep<32><<<ceil_div(RR*128*32,256),256,0,stream>>>(W1, 21, wtH, wtL);
  k_bsum<<<1,128,0,stream>>>(b1, bsv);
  k_fused<32,1><<<NN/32,256,0,stream>>>(
      (const unsigned short*)x0h, zsd, elist, off, wtH, wtL, bsv, n1w, n1b,
      h1h, h1l, (float*)0, query, batch, scrs, bmax, NN);

  // --- layer 2 ---
  k_wa<128><<<ceil_div(12*128,256),256,0,stream>>>(W2, as2, ad2, 128, wa);
  k_zsd128<<<ceil_div(NN*16,256),256,0,stream>>>(h1h, h1l, wa, zsd, NN);
  k_wprep<128><<<ceil_div(RR*128*128,256),256,0,stream>>>(W2, 128, wtH, wtL);
  k_bsum<<<1,128,0,stream>>>(b2, bsv);
  k_fused<128,2><<<NN/32,256,0,stream>>>(
      h1h, zsd, elist, off, wtH, wtL, bsv, n2w, n2b,
      (unsigned short*)0, (unsigned short*)0, h2, query, batch, scrs, bmax, NN);

  // --- attention pooling ---
  k_pool<<<BB,128,0,stream>>>(h2, scrs, segst, bmax, pool, BB);
  k_outgemm<<<BB,128,0,stream>>>(pool, projW, projb, out, BB);
}

// Round 8
// 924.090 us; speedup vs baseline: 1.3175x; 1.3175x over previous
//
#include <hip/hip_runtime.h>
#include <math.h>

#define NN   100000
#define EE   800000
#define RR   6
#define BB   1000
#define HH   128
#define MM   (RR*NN)
#define NBPR ((NN + 255) >> 8)
#define NBK  (RR * NBPR)
#define CH   4096

static inline int ceil_div(int a, int b){ return (a+b-1)/b; }

typedef __attribute__((ext_vector_type(8))) short bf16x8;
typedef __attribute__((ext_vector_type(4))) short bf16x4;
typedef __attribute__((ext_vector_type(4))) float f32x4;

__device__ __forceinline__ unsigned fenc(float f){
  unsigned u = __float_as_uint(f);
  return (u & 0x80000000u) ? ~u : (u | 0x80000000u);
}
__device__ __forceinline__ float fdec(unsigned u){
  return __uint_as_float((u & 0x80000000u) ? (u & 0x7fffffffu) : ~u);
}
__device__ __forceinline__ unsigned short f2bf(float f){
  unsigned u = __float_as_uint(f);
  return (unsigned short)((u + 0x7fffu + ((u >> 16) & 1u)) >> 16);
}
__device__ __forceinline__ float bf2f(unsigned short h){
  return __uint_as_float(((unsigned)h) << 16);
}

// ================= bucketed CSR build (proven) =================
__global__ void k_bcount(const int* __restrict__ edges, int* __restrict__ bcnt)
{
  __shared__ int hist[NBPR];
  int t = threadIdx.x;
  const int nch = (EE + CH - 1) / CH;
  int r = blockIdx.x / nch, c = blockIdx.x - r*nch;
  for (int i = t; i < NBPR; i += 256) hist[i] = 0;
  __syncthreads();
  const int* dptr = edges + (size_t)r*2*EE + EE;
  int e0 = c*CH, e1 = min(EE, e0 + CH);
  for (int i = e0 + t; i < e1; i += 256)
    atomicAdd(&hist[dptr[i] >> 8], 1);
  __syncthreads();
  for (int i = t; i < NBPR; i += 256) {
    int h = hist[i];
    if (h) atomicAdd(&bcnt[r*NBPR + i], h);
  }
}

__global__ void k_bscan(const int* __restrict__ bcnt, int* __restrict__ boff,
                        int* __restrict__ off)
{
  __shared__ int sh[256];
  int t = threadIdx.x;
  int carry = 0;
  for (int c = 0; c < NBK; c += 256) {
    int idx = c + t;
    int v = (idx < NBK) ? bcnt[idx] : 0;
    sh[t] = v;
    __syncthreads();
    for (int o = 1; o < 256; o <<= 1) {
      int add = (t >= o) ? sh[t-o] : 0;
      __syncthreads();
      sh[t] += add;
      __syncthreads();
    }
    int incl = sh[t];
    int tot  = sh[255];
    if (idx < NBK) boff[idx] = carry + incl - v;
    __syncthreads();
    carry += tot;
  }
  if (t == 0) { boff[NBK] = carry; off[MM] = carry; }
}

__global__ void k_binscatter(const int* __restrict__ edges, int* __restrict__ bcur,
                             unsigned* __restrict__ ebkt)
{
  __shared__ int hist[NBPR];
  __shared__ int base[NBPR];
  int t = threadIdx.x;
  const int nch = (EE + CH - 1) / CH;
  int r = blockIdx.x / nch, c = blockIdx.x - r*nch;
  for (int i = t; i < NBPR; i += 256) hist[i] = 0;
  __syncthreads();
  const int* sptr = edges + (size_t)r*2*EE;
  const int* dptr = sptr + EE;
  int e0 = c*CH, e1 = min(EE, e0 + CH);
  for (int i = e0 + t; i < e1; i += 256)
    atomicAdd(&hist[dptr[i] >> 8], 1);
  __syncthreads();
  for (int i = t; i < NBPR; i += 256) {
    int h = hist[i];
    base[i] = h ? atomicAdd(&bcur[r*NBPR + i], h) : 0;
    hist[i] = 0;
  }
  __syncthreads();
  for (int i = e0 + t; i < e1; i += 256) {
    int dst = dptr[i];
    int b = dst >> 8;
    int slot = base[b] + atomicAdd(&hist[b], 1);
    ebkt[slot] = ((unsigned)sptr[i] << 8) | (unsigned)(dst & 255);
  }
}

__global__ void k_bbuild(const unsigned* __restrict__ ebkt, const int* __restrict__ boff,
                         int* __restrict__ off, int* __restrict__ elist)
{
  __shared__ int cnt[256];
  __shared__ int sc[256];
  __shared__ int cur[256];
  int t = threadIdx.x;
  int bb = blockIdx.x;
  int e0 = boff[bb], e1 = boff[bb+1];
  cnt[t] = 0;
  __syncthreads();
  for (int i = e0 + t; i < e1; i += 256)
    atomicAdd(&cnt[ebkt[i] & 255u], 1);
  __syncthreads();
  sc[t] = cnt[t];
  __syncthreads();
  for (int o = 1; o < 256; o <<= 1) {
    int add = (t >= o) ? sc[t-o] : 0;
    __syncthreads();
    sc[t] += add;
    __syncthreads();
  }
  int excl = sc[t] - cnt[t];
  int r = bb / NBPR, b = bb - r*NBPR;
  int dst = b*256 + t;
  if (dst < NN) off[r*NN + dst] = e0 + excl;
  cur[t] = e0 + excl;
  __syncthreads();
  for (int i = e0 + t; i < e1; i += 256) {
    unsigned w = ebkt[i];
    int slot = atomicAdd(&cur[w & 255u], 1);
    elist[slot] = (int)(w >> 8);
  }
}

// ================= feature prep (bf16 hi/lo planes, K padded 21->32) =================
__global__ void k_featprep(const float* __restrict__ x_all, const float* __restrict__ pos_table,
                           short* __restrict__ x0h, short* __restrict__ x0l)
{
  int gid = blockIdx.x*256 + threadIdx.x;
  if (gid >= NN*32) return;
  int nidx = gid >> 5, c = gid & 31;
  float v = 0.f;
  if (c < 13) {
    int scl = (c < 5) ? c : c + 1;
    v = x_all[nidx*14 + scl];
  } else if (c < 21) {
    int pi = (int)x_all[nidx*14 + 5];
    pi = pi < 0 ? 0 : (pi > 23 ? 23 : pi);
    v = pos_table[pi*8 + (c - 13)];
  }
  unsigned short h = f2bf(v);
  unsigned short l = f2bf(v - bf2f(h));
  x0h[gid] = (short)h;
  x0l[gid] = (short)l;
}

// ================= weight prep =================
template<int KP>
__global__ void k_wprep(const float* __restrict__ W, int K,
                        short* __restrict__ Wh, short* __restrict__ Wl)
{
  int gid = blockIdx.x*256 + threadIdx.x;
  if (gid >= RR*128*KP) return;
  int r = gid / (128*KP);
  int rem = gid - r*(128*KP);
  int nn = rem / KP, k = rem - nn*KP;
  float v = (k < K) ? W[((size_t)r*K + k)*128 + nn] : 0.f;
  unsigned short h = f2bf(v);
  unsigned short l = f2bf(v - bf2f(h));
  Wh[gid] = (short)h;
  Wl[gid] = (short)l;
}

// ================= wa: precompute W_r @ a =================
template<int KP>
__global__ void k_wa(const float* __restrict__ W, const float* __restrict__ as,
                     const float* __restrict__ ad, int K, float* __restrict__ wa)
{
  int idx = blockIdx.x*256 + threadIdx.x;
  if (idx >= 12*KP) return;
  int rr = idx / KP, k = idx - rr*KP;
  int r = (rr < 6) ? rr : rr - 6;
  const float* a = ((rr < 6) ? as : ad) + (size_t)r*HH;
  float s = 0.f;
  if (k < K) {
    const float* wrow = W + ((size_t)r*K + k)*128;
    #pragma unroll 8
    for (int h = 0; h < 128; ++h) s = fmaf(wrow[h], a[h], s);
  }
  wa[idx] = s;
}

// ================= zsd: layer-1 z-scores [12][N] =================
__global__ void k_zsd32(const short* __restrict__ xh, const short* __restrict__ xl,
                        const float* __restrict__ wa, float* __restrict__ zsd, int n)
{
  __shared__ float w[12*32];
  int tid = threadIdx.x;
  for (int i = tid; i < 12*32; i += 256) w[i] = wa[i];
  __syncthreads();
  int g = blockIdx.x*256 + tid;
  if (g >= n) return;
  float v[32];
  #pragma unroll
  for (int c = 0; c < 4; ++c) {
    uint4 vh = *(const uint4*)(xh + (size_t)g*32 + c*8);
    uint4 vl = *(const uint4*)(xl + (size_t)g*32 + c*8);
    const unsigned short* hp = (const unsigned short*)&vh;
    const unsigned short* lp = (const unsigned short*)&vl;
    #pragma unroll
    for (int j = 0; j < 8; ++j) v[c*8+j] = bf2f(hp[j]) + bf2f(lp[j]);
  }
  #pragma unroll
  for (int rr = 0; rr < 12; ++rr) {
    float d = 0.f;
    #pragma unroll
    for (int k = 0; k < 32; ++k) d = fmaf(v[k], w[rr*32+k], d);
    zsd[(size_t)rr*n + g] = d;
  }
}

// ================= layer-1 aggregation: 16-lane group per dst, 6 relations =========
// gathers x0h (bf16, 64B rows); writes agg bf16 hi/lo [6][N][32]
__global__ void k_agg1(const unsigned short* __restrict__ x0h, const float* __restrict__ zsd,
                       const int* __restrict__ elist, const int* __restrict__ off,
                       unsigned short* __restrict__ aggH, unsigned short* __restrict__ aggL,
                       int n)
{
  int gid = blockIdx.x*256 + threadIdx.x;
  int g = gid >> 4;
  int l = threadIdx.x & 15;
  if (g >= n) return;
  int sub = l >> 2, ch = l & 3;

  for (int rel = 0; rel < RR; ++rel) {
    const float* zsr = zsd + (size_t)rel*n;
    const float* zdr = zsd + (size_t)(6+rel)*n;
    int o0 = off[(size_t)rel*NN + g];
    int deg = off[(size_t)rel*NN + g + 1] - o0;
    float acc[8] = {0,0,0,0,0,0,0,0};
    float inv = 0.f;
    if (deg > 0) {
      float zdd = zdr[g];
      float m = -3.4e38f, es = 0.f;
      for (int i = l; i < deg; i += 16) {
        float z = zsr[elist[o0+i]] + zdd;
        z = (z > 0.f) ? z : 0.2f*z;
        float mn = fmaxf(m, z);
        es = es*__expf(m - mn) + __expf(z - mn);
        m = mn;
      }
      #pragma unroll
      for (int o = 1; o <= 8; o <<= 1) {
        float mo = __shfl_xor(m, o), eo = __shfl_xor(es, o);
        float mn = fmaxf(m, mo);
        es = es*__expf(m - mn) + eo*__expf(mo - mn);
        m = mn;
      }
      inv = 1.f / es;
      for (int base = 0; base < deg; base += 4) {
        int i = base + sub;
        float ew = 0.f; int ss = 0;
        if (i < deg) {
          ss = elist[o0+i];
          float z = zsr[ss] + zdd;
          z = (z > 0.f) ? z : 0.2f*z;
          ew = __expf(z - m);
        }
        uint4 v = *(const uint4*)(x0h + (size_t)ss*32 + ch*8);
        acc[0] = fmaf(ew, __uint_as_float(v.x << 16),         acc[0]);
        acc[1] = fmaf(ew, __uint_as_float(v.x & 0xffff0000u), acc[1]);
        acc[2] = fmaf(ew, __uint_as_float(v.y << 16),         acc[2]);
        acc[3] = fmaf(ew, __uint_as_float(v.y & 0xffff0000u), acc[3]);
        acc[4] = fmaf(ew, __uint_as_float(v.z << 16),         acc[4]);
        acc[5] = fmaf(ew, __uint_as_float(v.z & 0xffff0000u), acc[5]);
        acc[6] = fmaf(ew, __uint_as_float(v.w << 16),         acc[6]);
        acc[7] = fmaf(ew, __uint_as_float(v.w & 0xffff0000u), acc[7]);
      }
      #pragma unroll
      for (int j = 0; j < 8; ++j) {
        acc[j] += __shfl_xor(acc[j], 4);
        acc[j] += __shfl_xor(acc[j], 8);
      }
    }
    if (sub == 0) {
      uint4 ph, pl;
      unsigned* php = (unsigned*)&ph; unsigned* plp = (unsigned*)&pl;
      #pragma unroll
      for (int j2 = 0; j2 < 4; ++j2) {
        float a0 = acc[2*j2]   * inv;
        float a1 = acc[2*j2+1] * inv;
        unsigned short h0 = f2bf(a0), h1 = f2bf(a1);
        php[j2] = ((unsigned)h1 << 16) | h0;
        plp[j2] = ((unsigned)f2bf(a1 - bf2f(h1)) << 16) | f2bf(a0 - bf2f(h0));
      }
      size_t o = ((size_t)rel*n + g)*32 + ch*8;
      *(uint4*)(aggH + o) = ph;
      *(uint4*)(aggL + o) = pl;
    }
  }
}

// ================= layer-1 concat-GEMM (K=6x32) + GELU+LN epilogue =============
__device__ __forceinline__ bf16x8 ldfragG(const short* __restrict__ p, int row, int kb, int KP_)
{
  bf16x4 a = *(const bf16x4*)(p + (size_t)row*KP_ + kb);
  bf16x4 b = *(const bf16x4*)(p + (size_t)row*KP_ + kb + 16);
  return __builtin_shufflevector(a, b, 0,1,2,3,4,5,6,7);
}

__global__ __launch_bounds__(256, 4)
void k_gemm1(const short* __restrict__ aggH, const short* __restrict__ aggL,
             const short* __restrict__ Wh, const short* __restrict__ Wl,
             const float* __restrict__ bsv,
             const float* __restrict__ nw, const float* __restrict__ nb,
             unsigned short* __restrict__ Yh, unsigned short* __restrict__ Yl, int n)
{
  __shared__ __align__(16) float Cs[32*136];
  int tid = threadIdx.x;
  int r0 = blockIdx.x * 32;
  int wid = tid >> 6, lane = tid & 63;
  int lr = lane & 15, lg = lane >> 4;
  int rt = wid >> 1;
  int c0 = (wid & 1) * 4;
  int arow = r0 + rt*16 + lr;
  int kb = 4*lg;
  f32x4 acct[4] = {{0,0,0,0},{0,0,0,0},{0,0,0,0},{0,0,0,0}};

  for (int rel = 0; rel < RR; ++rel) {
    const short* Ahr = aggH + (size_t)rel*n*32;
    const short* Alr = aggL + (size_t)rel*n*32;
    const short* Whr = Wh + (size_t)rel*128*32;
    const short* Wlr = Wl + (size_t)rel*128*32;
    bf16x8 ah = ldfragG(Ahr, arow, kb, 32);
    bf16x8 al = ldfragG(Alr, arow, kb, 32);
    #pragma unroll
    for (int t = 0; t < 4; ++t) {
      int wrow = (c0 + t)*16 + lr;
      bf16x8 whf = ldfragG(Whr, wrow, kb, 32);
      bf16x8 wlf = ldfragG(Wlr, wrow, kb, 32);
      acct[t] = __builtin_amdgcn_mfma_f32_16x16x32_bf16(ah, whf, acct[t], 0, 0, 0);
      acct[t] = __builtin_amdgcn_mfma_f32_16x16x32_bf16(al, whf, acct[t], 0, 0, 0);
      acct[t] = __builtin_amdgcn_mfma_f32_16x16x32_bf16(ah, wlf, acct[t], 0, 0, 0);
    }
  }

  // epilogue: bias + gelu -> Cs, per-row LN, bf16 hi/lo out
  #pragma unroll
  for (int t = 0; t < 4; ++t)
    #pragma unroll
    for (int v = 0; v < 4; ++v) {
      int row = rt*16 + lg*4 + v;
      int col = (c0 + t)*16 + lr;
      float x = acct[t][v] + bsv[col];
      Cs[row*136 + col] = 0.5f*x*(1.f + erff(x*0.70710678118654752f));
    }
  __syncthreads();
  {
    int r = tid >> 3, sg = tid & 7;
    float vals[16];
    float s = 0.f;
    #pragma unroll
    for (int i = 0; i < 16; ++i) { vals[i] = Cs[r*136 + sg*16 + i]; s += vals[i]; }
    s += __shfl_xor(s, 1); s += __shfl_xor(s, 2); s += __shfl_xor(s, 4);
    float mu = s * (1.f/128.f);
    float var = 0.f;
    #pragma unroll
    for (int i = 0; i < 16; ++i) { vals[i] -= mu; var += vals[i]*vals[i]; }
    var += __shfl_xor(var, 1); var += __shfl_xor(var, 2); var += __shfl_xor(var, 4);
    float inv = 1.f / sqrtf(var*(1.f/128.f) + 1e-5f);
    int g = r0 + r;
    uint4 ph0, ph1, pl0, pl1;
    unsigned* php0 = (unsigned*)&ph0; unsigned* php1 = (unsigned*)&ph1;
    unsigned* plp0 = (unsigned*)&pl0; unsigned* plp1 = (unsigned*)&pl1;
    #pragma unroll
    for (int j2 = 0; j2 < 8; ++j2) {
      int c = sg*16 + 2*j2;
      float y0 = vals[2*j2]  *inv*nw[c]   + nb[c];
      float y1 = vals[2*j2+1]*inv*nw[c+1] + nb[c+1];
      unsigned short h0 = f2bf(y0), h1 = f2bf(y1);
      unsigned hw = ((unsigned)h1 << 16) | h0;
      unsigned lw = ((unsigned)f2bf(y1 - bf2f(h1)) << 16) | f2bf(y0 - bf2f(h0));
      if (j2 < 4) { php0[j2] = hw; plp0[j2] = lw; }
      else        { php1[j2-4] = hw; plp1[j2-4] = lw; }
    }
    *(uint4*)(Yh + (size_t)g*128 + sg*16)     = ph0;
    *(uint4*)(Yh + (size_t)g*128 + sg*16 + 8) = ph1;
    *(uint4*)(Yl + (size_t)g*128 + sg*16)     = pl0;
    *(uint4*)(Yl + (size_t)g*128 + sg*16 + 8) = pl1;
  }
}

// ================= layer-2 MFMA GEMM (round-5, 3 relations via blockIdx.y) ========
__device__ __forceinline__ bf16x8 ldfrag_(const short* p, int row, int kb, int KP_, int smask)
{
  int xr = row & smask;
  int s0 = (((kb)      >> 3) ^ xr) * 8 + (kb & 7);
  int s1 = (((kb + 16) >> 3) ^ xr) * 8 + (kb & 7);
  bf16x4 a = *(const bf16x4*)(p + (size_t)row*KP_ + s0);
  bf16x4 b = *(const bf16x4*)(p + (size_t)row*KP_ + s1);
  return __builtin_shufflevector(a, b, 0,1,2,3,4,5,6,7);
}

template<int KP>
__global__ __launch_bounds__(256, 2)
void k_gemm_mfma(const short* __restrict__ Ah, const short* __restrict__ Al,
                 const short* __restrict__ WhAll, const short* __restrict__ WlAll,
                 const float* __restrict__ a_sAll, const float* __restrict__ a_dAll,
                 unsigned short* __restrict__ xpbAll, float* __restrict__ zsAll,
                 float* __restrict__ zdAll, int rbase, int n)
{
  constexpr int SLOTS = KP/8;
  constexpr int SMASK = (SLOTS >= 8) ? 7 : (SLOTS-1);
  __shared__ short lds[320*KP];
  constexpr int AH0 = 0, AL0 = 32*KP, WH0 = 64*KP, WL0 = 192*KP;
  int tid = threadIdx.x;
  int r0 = blockIdx.x * 32;
  int ry = blockIdx.y;
  const short* Wh = WhAll + (size_t)(rbase+ry)*128*KP;
  const short* Wl = WlAll + (size_t)(rbase+ry)*128*KP;
  const float* a_s = a_sAll + (size_t)(rbase+ry)*HH;
  const float* a_d = a_dAll + (size_t)(rbase+ry)*HH;
  unsigned short* xpb = xpbAll + (size_t)ry*n*128;
  float* zs = zsAll + (size_t)ry*n;
  float* zd = zdAll + (size_t)ry*n;

  for (int ch = tid; ch < 32*SLOTS; ch += 256) {
    int row = ch / SLOTS, slot = ch - row*SLOTS;
    int gr = r0 + row;
    int dsl = (slot ^ (row & SMASK)) * 8;
    bf16x8 vh, vl;
    if (gr < n) {
      vh = *(const bf16x8*)(Ah + (size_t)gr*KP + slot*8);
      vl = *(const bf16x8*)(Al + (size_t)gr*KP + slot*8);
    } else {
      #pragma unroll
      for (int q = 0; q < 8; ++q) { vh[q] = 0; vl[q] = 0; }
    }
    *(bf16x8*)(lds + AH0 + row*KP + dsl) = vh;
    *(bf16x8*)(lds + AL0 + row*KP + dsl) = vl;
  }
  for (int ch = tid; ch < 128*SLOTS; ch += 256) {
    int row = ch / SLOTS, slot = ch - row*SLOTS;
    int dsl = (slot ^ (row & SMASK)) * 8;
    *(bf16x8*)(lds + WH0 + row*KP + dsl) = *(const bf16x8*)(Wh + (size_t)row*KP + slot*8);
    *(bf16x8*)(lds + WL0 + row*KP + dsl) = *(const bf16x8*)(Wl + (size_t)row*KP + slot*8);
  }
  __syncthreads();

  int wid = tid >> 6, lane = tid & 63;
  int lr = lane & 15, lg = lane >> 4;
  int rt = wid >> 1;
  int c0 = (wid & 1) * 4;
  f32x4 acc[4] = {{0,0,0,0},{0,0,0,0},{0,0,0,0},{0,0,0,0}};
  int arow = rt*16 + lr;

  #pragma unroll
  for (int kc = 0; kc < KP/32; ++kc) {
    int kb = kc*32 + 4*lg;
    bf16x8 ah = ldfrag_(lds + AH0, arow, kb, KP, SMASK);
    bf16x8 al = ldfrag_(lds + AL0, arow, kb, KP, SMASK);
    #pragma unroll
    for (int t = 0; t < 4; ++t) {
      int wrow = (c0 + t)*16 + lr;
      bf16x8 wh = ldfrag_(lds + WH0, wrow, kb, KP, SMASK);
      bf16x8 wl = ldfrag_(lds + WL0, wrow, kb, KP, SMASK);
      acc[t] = __builtin_amdgcn_mfma_f32_16x16x32_bf16(ah, wh, acc[t], 0, 0, 0);
      acc[t] = __builtin_amdgcn_mfma_f32_16x16x32_bf16(ah, wl, acc[t], 0, 0, 0);
      acc[t] = __builtin_amdgcn_mfma_f32_16x16x32_bf16(al, wh, acc[t], 0, 0, 0);
    }
  }
  __syncthreads();

  float* Cs = (float*)lds;   // [32][136]
  #pragma unroll
  for (int t = 0; t < 4; ++t)
    #pragma unroll
    for (int v = 0; v < 4; ++v) {
      int row = rt*16 + lg*4 + v;
      int col = (c0 + t)*16 + lr;
      Cs[row*136 + col] = acc[t][v];
    }
  __syncthreads();

  {
    int r = tid >> 3, sg = tid & 7;
    float ps = 0.f, pd = 0.f;
    #pragma unroll
    for (int i = 0; i < 16; ++i) {
      int c = sg*16 + i;
      float x = Cs[r*136 + c];
      ps = fmaf(x, a_s[c], ps);
      pd = fmaf(x, a_d[c], pd);
    }
    ps += __shfl_xor(ps, 1); pd += __shfl_xor(pd, 1);
    ps += __shfl_xor(ps, 2); pd += __shfl_xor(pd, 2);
    ps += __shfl_xor(ps, 4); pd += __shfl_xor(pd, 4);
    int gr = r0 + r;
    if (sg == 0 && gr < n) { zs[gr] = ps; zd[gr] = pd; }
  }
  for (int i = tid; i < 32*16; i += 256) {
    int row = i >> 4, q = i & 15;
    int gr = r0 + row;
    if (gr < n) {
      const float* cp = Cs + row*136 + q*8;
      uint4 o;
      o.x = ((unsigned)f2bf(cp[1]) << 16) | f2bf(cp[0]);
      o.y = ((unsigned)f2bf(cp[3]) << 16) | f2bf(cp[2]);
      o.z = ((unsigned)f2bf(cp[5]) << 16) | f2bf(cp[4]);
      o.w = ((unsigned)f2bf(cp[7]) << 16) | f2bf(cp[6]);
      *(uint4*)(xpb + (size_t)gr*128 + q*8) = o;
    }
  }
}

// ================= layer-2 mega-agg (round-5): 3 relations, fused postln ==========
// FIN=0: write hacc. FIN=2: +hacc+bias, gelu+LN -> f32 + fused pool score.
template<int FIN>
__global__ void k_agg3(const unsigned short* __restrict__ xpb,  // [3][n][128]
                       const float* __restrict__ zs,            // [3][n]
                       const float* __restrict__ zd,
                       const int* __restrict__ elist,
                       const int* __restrict__ off,             // pre-offset by rbase*NN
                       float* __restrict__ hacc,
                       const float* __restrict__ bsum,
                       const float* __restrict__ nw, const float* __restrict__ nb,
                       float* __restrict__ Yf,
                       const float* __restrict__ q,
                       const int* __restrict__ batch,
                       float* __restrict__ scores, unsigned* __restrict__ bmax,
                       int n)
{
  int gid = blockIdx.x*256 + threadIdx.x;
  int g = gid >> 4;
  int l = threadIdx.x & 15;
  int gbase = threadIdx.x & 48;
  if (g >= n) return;

  float acc[8] = {0,0,0,0,0,0,0,0};

  #pragma unroll
  for (int r = 0; r < 3; ++r) {
    int o0 = off[(size_t)r*NN + g], o1 = off[(size_t)r*NN + g + 1];
    int deg = o1 - o0;
    if (deg <= 0) continue;
    const float* zsr = zs + (size_t)r*n;
    float zdd = zd[(size_t)r*n + g];

    float m = -3.4e38f;
    for (int i = l; i < deg; i += 16) {
      float z = zsr[elist[o0+i]] + zdd;
      z = (z > 0.f) ? z : 0.2f*z;
      m = fmaxf(m, z);
    }
    m = fmaxf(m, __shfl_xor(m, 1));
    m = fmaxf(m, __shfl_xor(m, 2));
    m = fmaxf(m, __shfl_xor(m, 4));
    m = fmaxf(m, __shfl_xor(m, 8));

    float tmp[8] = {0,0,0,0,0,0,0,0};
    float esum = 0.f;
    const unsigned short* xr = xpb + (size_t)r*n*128;
    for (int base = 0; base < deg; base += 16) {
      int i = base + l;
      float ew = 0.f; int s = 0;
      if (i < deg) {
        s = elist[o0+i];
        float z = zsr[s] + zdd;
        z = (z > 0.f) ? z : 0.2f*z;
        ew = __expf(z - m);
      }
      esum += ew;
      int cnt = min(16, deg - base);
      for (int t = 0; t < cnt; ++t) {
        float w = __shfl(ew, gbase + t);
        int ss = __shfl(s, gbase + t);
        const uint4 v = *(const uint4*)(xr + (size_t)ss*128 + l*8);
        tmp[0] = fmaf(w, __uint_as_float(v.x << 16),          tmp[0]);
        tmp[1] = fmaf(w, __uint_as_float(v.x & 0xffff0000u),  tmp[1]);
        tmp[2] = fmaf(w, __uint_as_float(v.y << 16),          tmp[2]);
        tmp[3] = fmaf(w, __uint_as_float(v.y & 0xffff0000u),  tmp[3]);
        tmp[4] = fmaf(w, __uint_as_float(v.z << 16),          tmp[4]);
        tmp[5] = fmaf(w, __uint_as_float(v.z & 0xffff0000u),  tmp[5]);
        tmp[6] = fmaf(w, __uint_as_float(v.w << 16),          tmp[6]);
        tmp[7] = fmaf(w, __uint_as_float(v.w & 0xffff0000u),  tmp[7]);
      }
    }
    esum += __shfl_xor(esum, 1);
    esum += __shfl_xor(esum, 2);
    esum += __shfl_xor(esum, 4);
    esum += __shfl_xor(esum, 8);
    float inv = 1.f / esum;
    #pragma unroll
    for (int j = 0; j < 8; ++j) acc[j] = fmaf(tmp[j], inv, acc[j]);
  }

  if (FIN == 0) {
    float* hp = hacc + (size_t)g*128 + l*8;
    float4 o0; o0.x = acc[0]; o0.y = acc[1]; o0.z = acc[2]; o0.w = acc[3];
    float4 o1; o1.x = acc[4]; o1.y = acc[5]; o1.z = acc[6]; o1.w = acc[7];
    *(float4*)hp = o0;
    *(float4*)(hp + 4) = o1;
  } else {
    const float* hp = hacc + (size_t)g*128 + l*8;
    float4 p0 = *(const float4*)hp;
    float4 p1 = *(const float4*)(hp + 4);
    float4 b0 = *(const float4*)(bsum + l*8);
    float4 b1 = *(const float4*)(bsum + l*8 + 4);
    acc[0] += p0.x + b0.x; acc[1] += p0.y + b0.y;
    acc[2] += p0.z + b0.z; acc[3] += p0.w + b0.w;
    acc[4] += p1.x + b1.x; acc[5] += p1.y + b1.y;
    acc[6] += p1.z + b1.z; acc[7] += p1.w + b1.w;
    float s = 0.f;
    #pragma unroll
    for (int j = 0; j < 8; ++j) {
      acc[j] = 0.5f*acc[j]*(1.f + erff(acc[j]*0.70710678118654752f));
      s += acc[j];
    }
    s += __shfl_xor(s, 1); s += __shfl_xor(s, 2);
    s += __shfl_xor(s, 4); s += __shfl_xor(s, 8);
    float mu = s * (1.f/128.f);
    float v = 0.f;
    #pragma unroll
    for (int j = 0; j < 8; ++j) { acc[j] -= mu; v += acc[j]*acc[j]; }
    v += __shfl_xor(v, 1); v += __shfl_xor(v, 2);
    v += __shfl_xor(v, 4); v += __shfl_xor(v, 8);
    v *= (1.f/128.f);
    float inv = 1.f / sqrtf(v + 1e-5f);
    float4 w0 = *(const float4*)(nw + l*8);
    float4 w1 = *(const float4*)(nw + l*8 + 4);
    float4 nb0 = *(const float4*)(nb + l*8);
    float4 nb1 = *(const float4*)(nb + l*8 + 4);
    float y[8];
    y[0] = acc[0]*inv*w0.x + nb0.x; y[1] = acc[1]*inv*w0.y + nb0.y;
    y[2] = acc[2]*inv*w0.z + nb0.z; y[3] = acc[3]*inv*w0.w + nb0.w;
    y[4] = acc[4]*inv*w1.x + nb1.x; y[5] = acc[5]*inv*w1.y + nb1.y;
    y[6] = acc[6]*inv*w1.z + nb1.z; y[7] = acc[7]*inv*w1.w + nb1.w;
    float* yp = Yf + (size_t)g*128 + l*8;
    float4 o0; o0.x = y[0]; o0.y = y[1]; o0.z = y[2]; o0.w = y[3];
    float4 o1; o1.x = y[4]; o1.y = y[5]; o1.z = y[6]; o1.w = y[7];
    *(float4*)yp = o0;
    *(float4*)(yp + 4) = o1;
    float4 q0 = *(const float4*)(q + l*8);
    float4 q1 = *(const float4*)(q + l*8 + 4);
    float sc = y[0]*q0.x + y[1]*q0.y + y[2]*q0.z + y[3]*q0.w
             + y[4]*q1.x + y[5]*q1.y + y[6]*q1.z + y[7]*q1.w;
    sc += __shfl_xor(sc, 1); sc += __shfl_xor(sc, 2);
    sc += __shfl_xor(sc, 4); sc += __shfl_xor(sc, 8);
    if (l == 0) {
      scores[g] = sc;
      atomicMax(&bmax[batch[g]], fenc(sc));
    }
  }
}

// ================= bias-sum =================
__global__ void k_bsum(const float* __restrict__ b, float* __restrict__ bs)
{
  int t = threadIdx.x;
  float s = 0.f;
  #pragma unroll
  for (int r = 0; r < RR; ++r) s += b[r*HH + t];
  bs[t] = s;
}

// ================= pooling =================
__global__ void k_segbounds(const int* __restrict__ batch, int* __restrict__ segst,
                            int n, int numB)
{
  int b = blockIdx.x*256 + threadIdx.x;
  if (b > numB) return;
  int lo = 0, hi = n;
  while (lo < hi) { int mid = (lo+hi) >> 1; if (batch[mid] < b) lo = mid+1; else hi = mid; }
  segst[b] = lo;
}

__global__ void k_pool(const float* __restrict__ X, const float* __restrict__ scores,
                       const int* __restrict__ segst, const unsigned* __restrict__ bmax,
                       float* __restrict__ pool, int numB)
{
  int b = blockIdx.x;
  int t = threadIdx.x;
  int s0 = segst[b], s1 = segst[b+1];
  float m = fdec(bmax[b]);
  float acc0 = 0.f, acc1 = 0.f, esum = 0.f;
  int i = s0;
  for (; i + 1 < s1; i += 2) {
    float e0 = __expf(scores[i] - m);
    float e1 = __expf(scores[i+1] - m);
    esum += e0 + e1;
    acc0 = fmaf(e0, X[(size_t)i*128 + t], acc0);
    acc1 = fmaf(e1, X[(size_t)(i+1)*128 + t], acc1);
  }
  if (i < s1) {
    float e0 = __expf(scores[i] - m);
    esum += e0;
    acc0 = fmaf(e0, X[(size_t)i*128 + t], acc0);
  }
  float inv = (s1 > s0) ? 1.f/esum : 0.f;
  pool[(size_t)b*128 + t] = (acc0 + acc1) * inv;
}

__global__ void k_outgemm(const float* __restrict__ pool, const float* __restrict__ projW,
                          const float* __restrict__ projb, float* __restrict__ out, int numB)
{
  int b = blockIdx.x;
  int j = threadIdx.x;
  __shared__ float p[128];
  p[j] = pool[(size_t)b*128 + j];
  __syncthreads();
  float acc = projb[j];
  #pragma unroll 16
  for (int k = 0; k < 128; ++k) acc = fmaf(p[k], projW[(size_t)k*128 + j], acc);
  out[(size_t)b*128 + j] = acc;
}

// ================= launcher =================
extern "C" void kernel_launch(void* const* d_in, const int* in_sizes, int n_in,
                              void* d_out, int out_size, void* d_ws, size_t ws_size,
                              hipStream_t stream)
{
  const float* x_all = (const float*)d_in[0];
  const int*   edges = (const int*)d_in[1];
  const int*   batch = (const int*)d_in[2];
  const float* pos_table = (const float*)d_in[3];
  const float* W1  = (const float*)d_in[4];
  const float* as1 = (const float*)d_in[5];
  const float* ad1 = (const float*)d_in[6];
  const float* b1  = (const float*)d_in[7];
  const float* W2  = (const float*)d_in[8];
  const float* as2 = (const float*)d_in[9];
  const float* ad2 = (const float*)d_in[10];
  const float* b2  = (const float*)d_in[11];
  const float* n1w = (const float*)d_in[12];
  const float* n1b = (const float*)d_in[13];
  const float* n2w = (const float*)d_in[14];
  const float* n2b = (const float*)d_in[15];
  const float* query = (const float*)d_in[16];
  const float* projW = (const float*)d_in[17];
  const float* projb = (const float*)d_in[18];
  float* out = (float*)d_out;
  (void)in_sizes; (void)n_in; (void)out_size; (void)ws_size;

  char* p = (char*)d_ws;
  auto alloc = [&](size_t b){ void* r = (void*)p; p += (b + 255) & ~(size_t)255; return r; };
  int*   off   = (int*)alloc((size_t)(MM+1)*sizeof(int));
  int*   elist = (int*)alloc((size_t)RR*EE*sizeof(int));
  int*   bcnt  = (int*)alloc((size_t)NBK*sizeof(int));
  int*   boff  = (int*)alloc((size_t)(NBK+1)*sizeof(int));
  int*   bcur  = (int*)alloc((size_t)NBK*sizeof(int));
  short* wtH   = (short*)alloc((size_t)RR*128*128*sizeof(short));
  short* wtL   = (short*)alloc((size_t)RR*128*128*sizeof(short));
  float* wa    = (float*)alloc((size_t)12*128*sizeof(float));
  float* zsd   = (float*)alloc((size_t)12*NN*sizeof(float));   // L1: [12][N]; L2: zs=[0..3N) zd=[3N..6N)
  float* bsv   = (float*)alloc(128*sizeof(float));
  int*   segst = (int*)alloc((size_t)(BB+1)*sizeof(int));
  unsigned* bmax = (unsigned*)alloc((size_t)BB*sizeof(unsigned));
  float* pool  = (float*)alloc((size_t)BB*HH*sizeof(float));
  float* scrs  = (float*)alloc((size_t)NN*sizeof(float));
  unsigned short* xpb = (unsigned short*)alloc((size_t)3*NN*128*sizeof(short)); // 76.8MB; aggH/aggL alias
  float* R1    = (float*)alloc((size_t)NN*128*sizeof(float));  // 51.2MB: ebkt -> x0h/x0l -> hacc
  float* R2    = (float*)alloc((size_t)NN*128*sizeof(float));  // 51.2MB: h1h/h1l -> h2

  unsigned* ebkt = (unsigned*)R1;
  short* x0h = (short*)R1;
  short* x0l = x0h + (size_t)NN*32;
  float* hacc = R1;
  unsigned short* h1h = (unsigned short*)R2;
  unsigned short* h1l = h1h + (size_t)NN*128;
  float* h2 = R2;
  unsigned short* aggH = (unsigned short*)xpb;          // [6][N][32]
  unsigned short* aggL = aggH + (size_t)RR*NN*32;
  float* zs = zsd;            // layer-2 planes
  float* zd = zsd + (size_t)3*NN;

  // --- CSR build ---
  const int nch = (EE + CH - 1) / CH;
  hipMemsetAsync(bcnt, 0, (size_t)NBK*sizeof(int), stream);
  k_bcount<<<RR*nch,256,0,stream>>>(edges, bcnt);
  k_bscan<<<1,256,0,stream>>>(bcnt, boff, off);
  hipMemcpyAsync(bcur, boff, (size_t)NBK*sizeof(int), hipMemcpyDeviceToDevice, stream);
  k_binscatter<<<RR*nch,256,0,stream>>>(edges, bcur, ebkt);
  k_bbuild<<<NBK,256,0,stream>>>(ebkt, boff, off, elist);

  // --- prep (featprep overwrites ebkt region AFTER bbuild) ---
  k_featprep<<<ceil_div(NN*32,256),256,0,stream>>>(x_all, pos_table, x0h, x0l);
  k_segbounds<<<ceil_div(BB+1,256),256,0,stream>>>(batch, segst, NN, BB);
  hipMemsetAsync(bmax, 0, (size_t)BB*sizeof(unsigned), stream);

  // --- layer 1: aggregate-then-project ---
  k_wa<32><<<ceil_div(12*32,256),256,0,stream>>>(W1, as1, ad1, 21, wa);
  k_zsd32<<<ceil_div(NN,256),256,0,stream>>>(x0h, x0l, wa, zsd, NN);
  k_wprep<32><<<ceil_div(RR*128*32,256),256,0,stream>>>(W1, 21, wtH, wtL);
  k_bsum<<<1,128,0,stream>>>(b1, bsv);
  k_agg1<<<ceil_div(NN*16,256),256,0,stream>>>((const unsigned short*)x0h, zsd, elist, off,
                                               aggH, aggL, NN);
  k_gemm1<<<ceil_div(NN,32),256,0,stream>>>((const short*)aggH, (const short*)aggL,
                                            wtH, wtL, bsv, n1w, n1b, h1h, h1l, NN);

  // --- layer 2: project-then-aggregate (round-5 structure) ---
  k_wprep<128><<<ceil_div(RR*128*128,256),256,0,stream>>>(W2, 128, wtH, wtL);
  k_bsum<<<1,128,0,stream>>>(b2, bsv);
  dim3 g3(ceil_div(NN,32), 3);
  int aggGrid = ceil_div(NN*16, 256);
  k_gemm_mfma<128><<<g3,256,0,stream>>>((const short*)h1h, (const short*)h1l,
                                        wtH, wtL, as2, ad2, xpb, zs, zd, 0, NN);
  k_agg3<0><<<aggGrid,256,0,stream>>>(xpb, zs, zd, elist, off, hacc,
      bsv, n2w, n2b, (float*)0, query, batch, scrs, bmax, NN);
  k_gemm_mfma<128><<<g3,256,0,stream>>>((const short*)h1h, (const short*)h1l,
                                        wtH, wtL, as2, ad2, xpb, zs, zd, 3, NN);
  k_agg3<2><<<aggGrid,256,0,stream>>>(xpb, zs, zd, elist, off + (size_t)3*NN, hacc,
      bsv, n2w, n2b, h2, query, batch, scrs, bmax, NN);

  // --- attention pooling ---
  k_pool<<<BB,128,0,stream>>>(h2, scrs, segst, bmax, pool, BB);
  k_outgemm<<<BB,128,0,stream>>>(pool, projW, projb, out, BB);
}

// Round 9
// 912.238 us; speedup vs baseline: 1.3346x; 1.0130x over previous
//
#include <hip/hip_runtime.h>
#include <math.h>

#define NN   100000
#define EE   800000
#define RR   6
#define BB   1000
#define HH   128
#define MM   (RR*NN)
#define NBPR ((NN + 255) >> 8)
#define NBK  (RR * NBPR)
#define CH   4096
#define CAP  4096     // fixed capacity per bucket in ebkt staging

static inline int ceil_div(int a, int b){ return (a+b-1)/b; }

typedef __attribute__((ext_vector_type(8))) short bf16x8;
typedef __attribute__((ext_vector_type(4))) short bf16x4;
typedef __attribute__((ext_vector_type(4))) float f32x4;

__device__ __forceinline__ unsigned fenc(float f){
  unsigned u = __float_as_uint(f);
  return (u & 0x80000000u) ? ~u : (u | 0x80000000u);
}
__device__ __forceinline__ float fdec(unsigned u){
  return __uint_as_float((u & 0x80000000u) ? (u & 0x7fffffffu) : ~u);
}
__device__ __forceinline__ unsigned short f2bf(float f){
  unsigned u = __float_as_uint(f);
  return (unsigned short)((u + 0x7fffu + ((u >> 16) & 1u)) >> 16);
}
__device__ __forceinline__ float bf2f(unsigned short h){
  return __uint_as_float(((unsigned)h) << 16);
}

// ================= CSR build: fixed-capacity binning (no count pass) =================
__global__ void k_binscatter(const int* __restrict__ edges, int* __restrict__ bcur,
                             unsigned* __restrict__ ebkt)
{
  __shared__ int hist[NBPR];
  __shared__ int base[NBPR];
  int t = threadIdx.x;
  const int nch = (EE + CH - 1) / CH;
  int r = blockIdx.x / nch, c = blockIdx.x - r*nch;
  for (int i = t; i < NBPR; i += 256) hist[i] = 0;
  __syncthreads();
  const int* sptr = edges + (size_t)r*2*EE;
  const int* dptr = sptr + EE;
  int e0 = c*CH, e1 = min(EE, e0 + CH);
  for (int i = e0 + t; i < e1; i += 256)
    atomicAdd(&hist[dptr[i] >> 8], 1);
  __syncthreads();
  for (int i = t; i < NBPR; i += 256) {
    int h = hist[i];
    int gb = r*NBPR + i;
    base[i] = h ? (gb*CAP + atomicAdd(&bcur[gb], h)) : 0;
    hist[i] = 0;
  }
  __syncthreads();
  for (int i = e0 + t; i < e1; i += 256) {
    int dst = dptr[i];
    int b = dst >> 8;
    int slot = base[b] + atomicAdd(&hist[b], 1);
    ebkt[slot] = ((unsigned)sptr[i] << 8) | (unsigned)(dst & 255);
  }
}

__global__ void k_bscan(const int* __restrict__ bcur, int* __restrict__ boff,
                        int* __restrict__ off)
{
  __shared__ int sh[256];
  int t = threadIdx.x;
  int carry = 0;
  for (int c = 0; c < NBK; c += 256) {
    int idx = c + t;
    int v = (idx < NBK) ? bcur[idx] : 0;
    sh[t] = v;
    __syncthreads();
    for (int o = 1; o < 256; o <<= 1) {
      int add = (t >= o) ? sh[t-o] : 0;
      __syncthreads();
      sh[t] += add;
      __syncthreads();
    }
    int incl = sh[t];
    int tot  = sh[255];
    if (idx < NBK) boff[idx] = carry + incl - v;
    __syncthreads();
    carry += tot;
  }
  if (t == 0) { boff[NBK] = carry; off[MM] = carry; }
}

__global__ void k_bbuild(const unsigned* __restrict__ ebkt, const int* __restrict__ bcur,
                         const int* __restrict__ boff,
                         int* __restrict__ off, int* __restrict__ elist)
{
  __shared__ int cnt[256];
  __shared__ int sc[256];
  __shared__ int cur[256];
  int t = threadIdx.x;
  int bb = blockIdx.x;
  int e0r = bb*CAP, e1r = e0r + bcur[bb];
  int w0 = boff[bb];
  cnt[t] = 0;
  __syncthreads();
  for (int i = e0r + t; i < e1r; i += 256)
    atomicAdd(&cnt[ebkt[i] & 255u], 1);
  __syncthreads();
  sc[t] = cnt[t];
  __syncthreads();
  for (int o = 1; o < 256; o <<= 1) {
    int add = (t >= o) ? sc[t-o] : 0;
    __syncthreads();
    sc[t] += add;
    __syncthreads();
  }
  int excl = sc[t] - cnt[t];
  int r = bb / NBPR, b = bb - r*NBPR;
  int dst = b*256 + t;
  if (dst < NN) off[r*NN + dst] = w0 + excl;
  cur[t] = w0 + excl;
  __syncthreads();
  for (int i = e0r + t; i < e1r; i += 256) {
    unsigned w = ebkt[i];
    int slot = atomicAdd(&cur[w & 255u], 1);
    elist[slot] = (int)(w >> 8);
  }
}

// ================= feature prep (bf16 hi/lo planes, K padded 21->32) =================
__global__ void k_featprep(const float* __restrict__ x_all, const float* __restrict__ pos_table,
                           short* __restrict__ x0h, short* __restrict__ x0l)
{
  int gid = blockIdx.x*256 + threadIdx.x;
  if (gid >= NN*32) return;
  int nidx = gid >> 5, c = gid & 31;
  float v = 0.f;
  if (c < 13) {
    int scl = (c < 5) ? c : c + 1;
    v = x_all[nidx*14 + scl];
  } else if (c < 21) {
    int pi = (int)x_all[nidx*14 + 5];
    pi = pi < 0 ? 0 : (pi > 23 ? 23 : pi);
    v = pos_table[pi*8 + (c - 13)];
  }
  unsigned short h = f2bf(v);
  unsigned short l = f2bf(v - bf2f(h));
  x0h[gid] = (short)h;
  x0l[gid] = (short)l;
}

// ================= weight prep =================
template<int KP>
__global__ void k_wprep(const float* __restrict__ W, int K,
                        short* __restrict__ Wh, short* __restrict__ Wl)
{
  int gid = blockIdx.x*256 + threadIdx.x;
  if (gid >= RR*128*KP) return;
  int r = gid / (128*KP);
  int rem = gid - r*(128*KP);
  int nn = rem / KP, k = rem - nn*KP;
  float v = (k < K) ? W[((size_t)r*K + k)*128 + nn] : 0.f;
  unsigned short h = f2bf(v);
  unsigned short l = f2bf(v - bf2f(h));
  Wh[gid] = (short)h;
  Wl[gid] = (short)l;
}

// ================= wa: precompute W_r @ a =================
template<int KP>
__global__ void k_wa(const float* __restrict__ W, const float* __restrict__ as,
                     const float* __restrict__ ad, int K, float* __restrict__ wa)
{
  int idx = blockIdx.x*256 + threadIdx.x;
  if (idx >= 12*KP) return;
  int rr = idx / KP, k = idx - rr*KP;
  int r = (rr < 6) ? rr : rr - 6;
  const float* a = ((rr < 6) ? as : ad) + (size_t)r*HH;
  float s = 0.f;
  if (k < K) {
    const float* wrow = W + ((size_t)r*K + k)*128;
    #pragma unroll 8
    for (int h = 0; h < 128; ++h) s = fmaf(wrow[h], a[h], s);
  }
  wa[idx] = s;
}

// ================= zsd: layer-1 z-scores [12][N] =================
__global__ void k_zsd32(const short* __restrict__ xh, const short* __restrict__ xl,
                        const float* __restrict__ wa, float* __restrict__ zsd, int n)
{
  __shared__ float w[12*32];
  int tid = threadIdx.x;
  for (int i = tid; i < 12*32; i += 256) w[i] = wa[i];
  __syncthreads();
  int g = blockIdx.x*256 + tid;
  if (g >= n) return;
  float v[32];
  #pragma unroll
  for (int c = 0; c < 4; ++c) {
    uint4 vh = *(const uint4*)(xh + (size_t)g*32 + c*8);
    uint4 vl = *(const uint4*)(xl + (size_t)g*32 + c*8);
    const unsigned short* hp = (const unsigned short*)&vh;
    const unsigned short* lp = (const unsigned short*)&vl;
    #pragma unroll
    for (int j = 0; j < 8; ++j) v[c*8+j] = bf2f(hp[j]) + bf2f(lp[j]);
  }
  #pragma unroll
  for (int rr = 0; rr < 12; ++rr) {
    float d = 0.f;
    #pragma unroll
    for (int k = 0; k < 32; ++k) d = fmaf(v[k], w[rr*32+k], d);
    zsd[(size_t)rr*n + g] = d;
  }
}

// ================= layer-1 aggregation (proven) =================
__global__ void k_agg1(const unsigned short* __restrict__ x0h, const float* __restrict__ zsd,
                       const int* __restrict__ elist, const int* __restrict__ off,
                       unsigned short* __restrict__ aggH, unsigned short* __restrict__ aggL,
                       int n)
{
  int gid = blockIdx.x*256 + threadIdx.x;
  int g = gid >> 4;
  int l = threadIdx.x & 15;
  if (g >= n) return;
  int sub = l >> 2, ch = l & 3;

  for (int rel = 0; rel < RR; ++rel) {
    const float* zsr = zsd + (size_t)rel*n;
    const float* zdr = zsd + (size_t)(6+rel)*n;
    int o0 = off[(size_t)rel*NN + g];
    int deg = off[(size_t)rel*NN + g + 1] - o0;
    float acc[8] = {0,0,0,0,0,0,0,0};
    float inv = 0.f;
    if (deg > 0) {
      float zdd = zdr[g];
      float m = -3.4e38f, es = 0.f;
      for (int i = l; i < deg; i += 16) {
        float z = zsr[elist[o0+i]] + zdd;
        z = (z > 0.f) ? z : 0.2f*z;
        float mn = fmaxf(m, z);
        es = es*__expf(m - mn) + __expf(z - mn);
        m = mn;
      }
      #pragma unroll
      for (int o = 1; o <= 8; o <<= 1) {
        float mo = __shfl_xor(m, o), eo = __shfl_xor(es, o);
        float mn = fmaxf(m, mo);
        es = es*__expf(m - mn) + eo*__expf(mo - mn);
        m = mn;
      }
      inv = 1.f / es;
      for (int base = 0; base < deg; base += 4) {
        int i = base + sub;
        float ew = 0.f; int ss = 0;
        if (i < deg) {
          ss = elist[o0+i];
          float z = zsr[ss] + zdd;
          z = (z > 0.f) ? z : 0.2f*z;
          ew = __expf(z - m);
        }
        uint4 v = *(const uint4*)(x0h + (size_t)ss*32 + ch*8);
        acc[0] = fmaf(ew, __uint_as_float(v.x << 16),         acc[0]);
        acc[1] = fmaf(ew, __uint_as_float(v.x & 0xffff0000u), acc[1]);
        acc[2] = fmaf(ew, __uint_as_float(v.y << 16),         acc[2]);
        acc[3] = fmaf(ew, __uint_as_float(v.y & 0xffff0000u), acc[3]);
        acc[4] = fmaf(ew, __uint_as_float(v.z << 16),         acc[4]);
        acc[5] = fmaf(ew, __uint_as_float(v.z & 0xffff0000u), acc[5]);
        acc[6] = fmaf(ew, __uint_as_float(v.w << 16),         acc[6]);
        acc[7] = fmaf(ew, __uint_as_float(v.w & 0xffff0000u), acc[7]);
      }
      #pragma unroll
      for (int j = 0; j < 8; ++j) {
        acc[j] += __shfl_xor(acc[j], 4);
        acc[j] += __shfl_xor(acc[j], 8);
      }
    }
    if (sub == 0) {
      uint4 ph, pl;
      unsigned* php = (unsigned*)&ph; unsigned* plp = (unsigned*)&pl;
      #pragma unroll
      for (int j2 = 0; j2 < 4; ++j2) {
        float a0 = acc[2*j2]   * inv;
        float a1 = acc[2*j2+1] * inv;
        unsigned short h0 = f2bf(a0), h1 = f2bf(a1);
        php[j2] = ((unsigned)h1 << 16) | h0;
        plp[j2] = ((unsigned)f2bf(a1 - bf2f(h1)) << 16) | f2bf(a0 - bf2f(h0));
      }
      size_t o = ((size_t)rel*n + g)*32 + ch*8;
      *(uint4*)(aggH + o) = ph;
      *(uint4*)(aggL + o) = pl;
    }
  }
}

// ================= layer-1 concat-GEMM (proven) =================
__device__ __forceinline__ bf16x8 ldfragG(const short* __restrict__ p, int row, int kb, int KP_)
{
  bf16x4 a = *(const bf16x4*)(p + (size_t)row*KP_ + kb);
  bf16x4 b = *(const bf16x4*)(p + (size_t)row*KP_ + kb + 16);
  return __builtin_shufflevector(a, b, 0,1,2,3,4,5,6,7);
}

__global__ __launch_bounds__(256, 4)
void k_gemm1(const short* __restrict__ aggH, const short* __restrict__ aggL,
             const short* __restrict__ Wh, const short* __restrict__ Wl,
             const float* __restrict__ bsv,
             const float* __restrict__ nw, const float* __restrict__ nb,
             unsigned short* __restrict__ Yh, unsigned short* __restrict__ Yl, int n)
{
  __shared__ __align__(16) float Cs[32*136];
  int tid = threadIdx.x;
  int r0 = blockIdx.x * 32;
  int wid = tid >> 6, lane = tid & 63;
  int lr = lane & 15, lg = lane >> 4;
  int rt = wid >> 1;
  int c0 = (wid & 1) * 4;
  int arow = r0 + rt*16 + lr;
  int kb = 4*lg;
  f32x4 acct[4] = {{0,0,0,0},{0,0,0,0},{0,0,0,0},{0,0,0,0}};

  for (int rel = 0; rel < RR; ++rel) {
    const short* Ahr = aggH + (size_t)rel*n*32;
    const short* Alr = aggL + (size_t)rel*n*32;
    const short* Whr = Wh + (size_t)rel*128*32;
    const short* Wlr = Wl + (size_t)rel*128*32;
    bf16x8 ah = ldfragG(Ahr, arow, kb, 32);
    bf16x8 al = ldfragG(Alr, arow, kb, 32);
    #pragma unroll
    for (int t = 0; t < 4; ++t) {
      int wrow = (c0 + t)*16 + lr;
      bf16x8 whf = ldfragG(Whr, wrow, kb, 32);
      bf16x8 wlf = ldfragG(Wlr, wrow, kb, 32);
      acct[t] = __builtin_amdgcn_mfma_f32_16x16x32_bf16(ah, whf, acct[t], 0, 0, 0);
      acct[t] = __builtin_amdgcn_mfma_f32_16x16x32_bf16(al, whf, acct[t], 0, 0, 0);
      acct[t] = __builtin_amdgcn_mfma_f32_16x16x32_bf16(ah, wlf, acct[t], 0, 0, 0);
    }
  }

  #pragma unroll
  for (int t = 0; t < 4; ++t)
    #pragma unroll
    for (int v = 0; v < 4; ++v) {
      int row = rt*16 + lg*4 + v;
      int col = (c0 + t)*16 + lr;
      float x = acct[t][v] + bsv[col];
      Cs[row*136 + col] = 0.5f*x*(1.f + erff(x*0.70710678118654752f));
    }
  __syncthreads();
  {
    int r = tid >> 3, sg = tid & 7;
    float vals[16];
    float s = 0.f;
    #pragma unroll
    for (int i = 0; i < 16; ++i) { vals[i] = Cs[r*136 + sg*16 + i]; s += vals[i]; }
    s += __shfl_xor(s, 1); s += __shfl_xor(s, 2); s += __shfl_xor(s, 4);
    float mu = s * (1.f/128.f);
    float var = 0.f;
    #pragma unroll
    for (int i = 0; i < 16; ++i) { vals[i] -= mu; var += vals[i]*vals[i]; }
    var += __shfl_xor(var, 1); var += __shfl_xor(var, 2); var += __shfl_xor(var, 4);
    float inv = 1.f / sqrtf(var*(1.f/128.f) + 1e-5f);
    int g = r0 + r;
    uint4 ph0, ph1, pl0, pl1;
    unsigned* php0 = (unsigned*)&ph0; unsigned* php1 = (unsigned*)&ph1;
    unsigned* plp0 = (unsigned*)&pl0; unsigned* plp1 = (unsigned*)&pl1;
    #pragma unroll
    for (int j2 = 0; j2 < 8; ++j2) {
      int c = sg*16 + 2*j2;
      float y0 = vals[2*j2]  *inv*nw[c]   + nb[c];
      float y1 = vals[2*j2+1]*inv*nw[c+1] + nb[c+1];
      unsigned short h0 = f2bf(y0), h1 = f2bf(y1);
      unsigned hw = ((unsigned)h1 << 16) | h0;
      unsigned lw = ((unsigned)f2bf(y1 - bf2f(h1)) << 16) | f2bf(y0 - bf2f(h0));
      if (j2 < 4) { php0[j2] = hw; plp0[j2] = lw; }
      else        { php1[j2-4] = hw; plp1[j2-4] = lw; }
    }
    *(uint4*)(Yh + (size_t)g*128 + sg*16)     = ph0;
    *(uint4*)(Yh + (size_t)g*128 + sg*16 + 8) = ph1;
    *(uint4*)(Yl + (size_t)g*128 + sg*16)     = pl0;
    *(uint4*)(Yl + (size_t)g*128 + sg*16 + 8) = pl1;
  }
}

// ================= layer-2 MFMA GEMM (proven; relations on blockIdx.y) ========
__device__ __forceinline__ bf16x8 ldfrag_(const short* p, int row, int kb, int KP_, int smask)
{
  int xr = row & smask;
  int s0 = (((kb)      >> 3) ^ xr) * 8 + (kb & 7);
  int s1 = (((kb + 16) >> 3) ^ xr) * 8 + (kb & 7);
  bf16x4 a = *(const bf16x4*)(p + (size_t)row*KP_ + s0);
  bf16x4 b = *(const bf16x4*)(p + (size_t)row*KP_ + s1);
  return __builtin_shufflevector(a, b, 0,1,2,3,4,5,6,7);
}

template<int KP>
__global__ __launch_bounds__(256, 2)
void k_gemm_mfma(const short* __restrict__ Ah, const short* __restrict__ Al,
                 const short* __restrict__ WhAll, const short* __restrict__ WlAll,
                 const float* __restrict__ a_sAll, const float* __restrict__ a_dAll,
                 unsigned short* __restrict__ xpbAll, float* __restrict__ zsAll,
                 float* __restrict__ zdAll, int rbase, int n)
{
  constexpr int SLOTS = KP/8;
  constexpr int SMASK = (SLOTS >= 8) ? 7 : (SLOTS-1);
  __shared__ short lds[320*KP];
  constexpr int AH0 = 0, AL0 = 32*KP, WH0 = 64*KP, WL0 = 192*KP;
  int tid = threadIdx.x;
  int r0 = blockIdx.x * 32;
  int ry = blockIdx.y;
  const short* Wh = WhAll + (size_t)(rbase+ry)*128*KP;
  const short* Wl = WlAll + (size_t)(rbase+ry)*128*KP;
  const float* a_s = a_sAll + (size_t)(rbase+ry)*HH;
  const float* a_d = a_dAll + (size_t)(rbase+ry)*HH;
  unsigned short* xpb = xpbAll + (size_t)ry*n*128;
  float* zs = zsAll + (size_t)ry*n;
  float* zd = zdAll + (size_t)ry*n;

  for (int ch = tid; ch < 32*SLOTS; ch += 256) {
    int row = ch / SLOTS, slot = ch - row*SLOTS;
    int gr = r0 + row;
    int dsl = (slot ^ (row & SMASK)) * 8;
    bf16x8 vh, vl;
    if (gr < n) {
      vh = *(const bf16x8*)(Ah + (size_t)gr*KP + slot*8);
      vl = *(const bf16x8*)(Al + (size_t)gr*KP + slot*8);
    } else {
      #pragma unroll
      for (int q = 0; q < 8; ++q) { vh[q] = 0; vl[q] = 0; }
    }
    *(bf16x8*)(lds + AH0 + row*KP + dsl) = vh;
    *(bf16x8*)(lds + AL0 + row*KP + dsl) = vl;
  }
  for (int ch = tid; ch < 128*SLOTS; ch += 256) {
    int row = ch / SLOTS, slot = ch - row*SLOTS;
    int dsl = (slot ^ (row & SMASK)) * 8;
    *(bf16x8*)(lds + WH0 + row*KP + dsl) = *(const bf16x8*)(Wh + (size_t)row*KP + slot*8);
    *(bf16x8*)(lds + WL0 + row*KP + dsl) = *(const bf16x8*)(Wl + (size_t)row*KP + slot*8);
  }
  __syncthreads();

  int wid = tid >> 6, lane = tid & 63;
  int lr = lane & 15, lg = lane >> 4;
  int rt = wid >> 1;
  int c0 = (wid & 1) * 4;
  f32x4 acc[4] = {{0,0,0,0},{0,0,0,0},{0,0,0,0},{0,0,0,0}};
  int arow = rt*16 + lr;

  #pragma unroll
  for (int kc = 0; kc < KP/32; ++kc) {
    int kb = kc*32 + 4*lg;
    bf16x8 ah = ldfrag_(lds + AH0, arow, kb, KP, SMASK);
    bf16x8 al = ldfrag_(lds + AL0, arow, kb, KP, SMASK);
    #pragma unroll
    for (int t = 0; t < 4; ++t) {
      int wrow = (c0 + t)*16 + lr;
      bf16x8 wh = ldfrag_(lds + WH0, wrow, kb, KP, SMASK);
      bf16x8 wl = ldfrag_(lds + WL0, wrow, kb, KP, SMASK);
      acc[t] = __builtin_amdgcn_mfma_f32_16x16x32_bf16(ah, wh, acc[t], 0, 0, 0);
      acc[t] = __builtin_amdgcn_mfma_f32_16x16x32_bf16(ah, wl, acc[t], 0, 0, 0);
      acc[t] = __builtin_amdgcn_mfma_f32_16x16x32_bf16(al, wh, acc[t], 0, 0, 0);
    }
  }
  __syncthreads();

  float* Cs = (float*)lds;   // [32][136]
  #pragma unroll
  for (int t = 0; t < 4; ++t)
    #pragma unroll
    for (int v = 0; v < 4; ++v) {
      int row = rt*16 + lg*4 + v;
      int col = (c0 + t)*16 + lr;
      Cs[row*136 + col] = acc[t][v];
    }
  __syncthreads();

  {
    int r = tid >> 3, sg = tid & 7;
    float ps = 0.f, pd = 0.f;
    #pragma unroll
    for (int i = 0; i < 16; ++i) {
      int c = sg*16 + i;
      float x = Cs[r*136 + c];
      ps = fmaf(x, a_s[c], ps);
      pd = fmaf(x, a_d[c], pd);
    }
    ps += __shfl_xor(ps, 1); pd += __shfl_xor(pd, 1);
    ps += __shfl_xor(ps, 2); pd += __shfl_xor(pd, 2);
    ps += __shfl_xor(ps, 4); pd += __shfl_xor(pd, 4);
    int gr = r0 + r;
    if (sg == 0 && gr < n) { zs[gr] = ps; zd[gr] = pd; }
  }
  for (int i = tid; i < 32*16; i += 256) {
    int row = i >> 4, q = i & 15;
    int gr = r0 + row;
    if (gr < n) {
      const float* cp = Cs + row*136 + q*8;
      uint4 o;
      o.x = ((unsigned)f2bf(cp[1]) << 16) | f2bf(cp[0]);
      o.y = ((unsigned)f2bf(cp[3]) << 16) | f2bf(cp[2]);
      o.z = ((unsigned)f2bf(cp[5]) << 16) | f2bf(cp[4]);
      o.w = ((unsigned)f2bf(cp[7]) << 16) | f2bf(cp[6]);
      *(uint4*)(xpb + (size_t)gr*128 + q*8) = o;
    }
  }
}

// ================= layer-2 mega-agg =================
// FIN=0: write hacc. FIN=2: +hacc+bias finalize. FIN=3: +bias finalize (no hacc).
template<int NREL, int FIN>
__global__ void k_agg3(const unsigned short* __restrict__ xpb,  // [NREL][n][128]
                       const float* __restrict__ zs,            // [NREL][n]
                       const float* __restrict__ zd,
                       const int* __restrict__ elist,
                       const int* __restrict__ off,
                       float* __restrict__ hacc,
                       const float* __restrict__ bsum,
                       const float* __restrict__ nw, const float* __restrict__ nb,
                       float* __restrict__ Yf,
                       const float* __restrict__ q,
                       const int* __restrict__ batch,
                       float* __restrict__ scores, unsigned* __restrict__ bmax,
                       int n)
{
  int gid = blockIdx.x*256 + threadIdx.x;
  int g = gid >> 4;
  int l = threadIdx.x & 15;
  int gbase = threadIdx.x & 48;
  if (g >= n) return;

  float acc[8] = {0,0,0,0,0,0,0,0};

  #pragma unroll
  for (int r = 0; r < NREL; ++r) {
    int o0 = off[(size_t)r*NN + g], o1 = off[(size_t)r*NN + g + 1];
    int deg = o1 - o0;
    if (deg <= 0) continue;
    const float* zsr = zs + (size_t)r*n;
    float zdd = zd[(size_t)r*n + g];

    float m = -3.4e38f;
    for (int i = l; i < deg; i += 16) {
      float z = zsr[elist[o0+i]] + zdd;
      z = (z > 0.f) ? z : 0.2f*z;
      m = fmaxf(m, z);
    }
    m = fmaxf(m, __shfl_xor(m, 1));
    m = fmaxf(m, __shfl_xor(m, 2));
    m = fmaxf(m, __shfl_xor(m, 4));
    m = fmaxf(m, __shfl_xor(m, 8));

    float tmp[8] = {0,0,0,0,0,0,0,0};
    float esum = 0.f;
    const unsigned short* xr = xpb + (size_t)r*n*128;
    for (int base = 0; base < deg; base += 16) {
      int i = base + l;
      float ew = 0.f; int s = 0;
      if (i < deg) {
        s = elist[o0+i];
        float z = zsr[s] + zdd;
        z = (z > 0.f) ? z : 0.2f*z;
        ew = __expf(z - m);
      }
      esum += ew;
      int cnt = min(16, deg - base);
      for (int t = 0; t < cnt; ++t) {
        float w = __shfl(ew, gbase + t);
        int ss = __shfl(s, gbase + t);
        const uint4 v = *(const uint4*)(xr + (size_t)ss*128 + l*8);
        tmp[0] = fmaf(w, __uint_as_float(v.x << 16),          tmp[0]);
        tmp[1] = fmaf(w, __uint_as_float(v.x & 0xffff0000u),  tmp[1]);
        tmp[2] = fmaf(w, __uint_as_float(v.y << 16),          tmp[2]);
        tmp[3] = fmaf(w, __uint_as_float(v.y & 0xffff0000u),  tmp[3]);
        tmp[4] = fmaf(w, __uint_as_float(v.z << 16),          tmp[4]);
        tmp[5] = fmaf(w, __uint_as_float(v.z & 0xffff0000u),  tmp[5]);
        tmp[6] = fmaf(w, __uint_as_float(v.w << 16),          tmp[6]);
        tmp[7] = fmaf(w, __uint_as_float(v.w & 0xffff0000u),  tmp[7]);
      }
    }
    esum += __shfl_xor(esum, 1);
    esum += __shfl_xor(esum, 2);
    esum += __shfl_xor(esum, 4);
    esum += __shfl_xor(esum, 8);
    float inv = 1.f / esum;
    #pragma unroll
    for (int j = 0; j < 8; ++j) acc[j] = fmaf(tmp[j], inv, acc[j]);
  }

  if (FIN == 0) {
    float* hp = hacc + (size_t)g*128 + l*8;
    float4 o0; o0.x = acc[0]; o0.y = acc[1]; o0.z = acc[2]; o0.w = acc[3];
    float4 o1; o1.x = acc[4]; o1.y = acc[5]; o1.z = acc[6]; o1.w = acc[7];
    *(float4*)hp = o0;
    *(float4*)(hp + 4) = o1;
  } else {
    if (FIN == 2) {
      const float* hp = hacc + (size_t)g*128 + l*8;
      float4 p0 = *(const float4*)hp;
      float4 p1 = *(const float4*)(hp + 4);
      acc[0] += p0.x; acc[1] += p0.y; acc[2] += p0.z; acc[3] += p0.w;
      acc[4] += p1.x; acc[5] += p1.y; acc[6] += p1.z; acc[7] += p1.w;
    }
    float4 b0 = *(const float4*)(bsum + l*8);
    float4 b1 = *(const float4*)(bsum + l*8 + 4);
    acc[0] += b0.x; acc[1] += b0.y; acc[2] += b0.z; acc[3] += b0.w;
    acc[4] += b1.x; acc[5] += b1.y; acc[6] += b1.z; acc[7] += b1.w;
    float s = 0.f;
    #pragma unroll
    for (int j = 0; j < 8; ++j) {
      acc[j] = 0.5f*acc[j]*(1.f + erff(acc[j]*0.70710678118654752f));
      s += acc[j];
    }
    s += __shfl_xor(s, 1); s += __shfl_xor(s, 2);
    s += __shfl_xor(s, 4); s += __shfl_xor(s, 8);
    float mu = s * (1.f/128.f);
    float v = 0.f;
    #pragma unroll
    for (int j = 0; j < 8; ++j) { acc[j] -= mu; v += acc[j]*acc[j]; }
    v += __shfl_xor(v, 1); v += __shfl_xor(v, 2);
    v += __shfl_xor(v, 4); v += __shfl_xor(v, 8);
    v *= (1.f/128.f);
    float inv = 1.f / sqrtf(v + 1e-5f);
    float4 w0 = *(const float4*)(nw + l*8);
    float4 w1 = *(const float4*)(nw + l*8 + 4);
    float4 nb0 = *(const float4*)(nb + l*8);
    float4 nb1 = *(const float4*)(nb + l*8 + 4);
    float y[8];
    y[0] = acc[0]*inv*w0.x + nb0.x; y[1] = acc[1]*inv*w0.y + nb0.y;
    y[2] = acc[2]*inv*w0.z + nb0.z; y[3] = acc[3]*inv*w0.w + nb0.w;
    y[4] = acc[4]*inv*w1.x + nb1.x; y[5] = acc[5]*inv*w1.y + nb1.y;
    y[6] = acc[6]*inv*w1.z + nb1.z; y[7] = acc[7]*inv*w1.w + nb1.w;
    float* yp = Yf + (size_t)g*128 + l*8;
    float4 o0; o0.x = y[0]; o0.y = y[1]; o0.z = y[2]; o0.w = y[3];
    float4 o1; o1.x = y[4]; o1.y = y[5]; o1.z = y[6]; o1.w = y[7];
    *(float4*)yp = o0;
    *(float4*)(yp + 4) = o1;
    float4 q0 = *(const float4*)(q + l*8);
    float4 q1 = *(const float4*)(q + l*8 + 4);
    float sc = y[0]*q0.x + y[1]*q0.y + y[2]*q0.z + y[3]*q0.w
             + y[4]*q1.x + y[5]*q1.y + y[6]*q1.z + y[7]*q1.w;
    sc += __shfl_xor(sc, 1); sc += __shfl_xor(sc, 2);
    sc += __shfl_xor(sc, 4); sc += __shfl_xor(sc, 8);
    if (l == 0) {
      scores[g] = sc;
      atomicMax(&bmax[batch[g]], fenc(sc));
    }
  }
}

// ================= bias-sum =================
__global__ void k_bsum(const float* __restrict__ b, float* __restrict__ bs)
{
  int t = threadIdx.x;
  float s = 0.f;
  #pragma unroll
  for (int r = 0; r < RR; ++r) s += b[r*HH + t];
  bs[t] = s;
}

// ================= pooling =================
__global__ void k_segbounds(const int* __restrict__ batch, int* __restrict__ segst,
                            int n, int numB)
{
  int b = blockIdx.x*256 + threadIdx.x;
  if (b > numB) return;
  int lo = 0, hi = n;
  while (lo < hi) { int mid = (lo+hi) >> 1; if (batch[mid] < b) lo = mid+1; else hi = mid; }
  segst[b] = lo;
}

__global__ void k_pool(const float* __restrict__ X, const float* __restrict__ scores,
                       const int* __restrict__ segst, const unsigned* __restrict__ bmax,
                       float* __restrict__ pool, int numB)
{
  int b = blockIdx.x;
  int t = threadIdx.x;
  int s0 = segst[b], s1 = segst[b+1];
  float m = fdec(bmax[b]);
  float acc0 = 0.f, acc1 = 0.f, esum = 0.f;
  int i = s0;
  for (; i + 1 < s1; i += 2) {
    float e0 = __expf(scores[i] - m);
    float e1 = __expf(scores[i+1] - m);
    esum += e0 + e1;
    acc0 = fmaf(e0, X[(size_t)i*128 + t], acc0);
    acc1 = fmaf(e1, X[(size_t)(i+1)*128 + t], acc1);
  }
  if (i < s1) {
    float e0 = __expf(scores[i] - m);
    esum += e0;
    acc0 = fmaf(e0, X[(size_t)i*128 + t], acc0);
  }
  float inv = (s1 > s0) ? 1.f/esum : 0.f;
  pool[(size_t)b*128 + t] = (acc0 + acc1) * inv;
}

__global__ void k_outgemm(const float* __restrict__ pool, const float* __restrict__ projW,
                          const float* __restrict__ projb, float* __restrict__ out, int numB)
{
  int b = blockIdx.x;
  int j = threadIdx.x;
  __shared__ float p[128];
  p[j] = pool[(size_t)b*128 + j];
  __syncthreads();
  float acc = projb[j];
  #pragma unroll 16
  for (int k = 0; k < 128; ++k) acc = fmaf(p[k], projW[(size_t)k*128 + j], acc);
  out[(size_t)b*128 + j] = acc;
}

// ================= launcher =================
extern "C" void kernel_launch(void* const* d_in, const int* in_sizes, int n_in,
                              void* d_out, int out_size, void* d_ws, size_t ws_size,
                              hipStream_t stream)
{
  const float* x_all = (const float*)d_in[0];
  const int*   edges = (const int*)d_in[1];
  const int*   batch = (const int*)d_in[2];
  const float* pos_table = (const float*)d_in[3];
  const float* W1  = (const float*)d_in[4];
  const float* as1 = (const float*)d_in[5];
  const float* ad1 = (const float*)d_in[6];
  const float* b1  = (const float*)d_in[7];
  const float* W2  = (const float*)d_in[8];
  const float* as2 = (const float*)d_in[9];
  const float* ad2 = (const float*)d_in[10];
  const float* b2  = (const float*)d_in[11];
  const float* n1w = (const float*)d_in[12];
  const float* n1b = (const float*)d_in[13];
  const float* n2w = (const float*)d_in[14];
  const float* n2b = (const float*)d_in[15];
  const float* query = (const float*)d_in[16];
  const float* projW = (const float*)d_in[17];
  const float* projb = (const float*)d_in[18];
  float* out = (float*)d_out;
  (void)in_sizes; (void)n_in; (void)out_size;

  const bool use6 = ws_size >= ((size_t)300 << 20);   // single-pass layer-2 if ws allows

  char* p = (char*)d_ws;
  auto alloc = [&](size_t b){ void* r = (void*)p; p += (b + 255) & ~(size_t)255; return r; };
  int*   off   = (int*)alloc((size_t)(MM+1)*sizeof(int));
  int*   elist = (int*)alloc((size_t)RR*EE*sizeof(int));
  int*   boff  = (int*)alloc((size_t)(NBK+1)*sizeof(int));
  int*   bcur  = (int*)alloc((size_t)NBK*sizeof(int));
  short* wtH   = (short*)alloc((size_t)RR*128*128*sizeof(short));
  short* wtL   = (short*)alloc((size_t)RR*128*128*sizeof(short));
  float* wa    = (float*)alloc((size_t)12*128*sizeof(float));
  float* zsd   = (float*)alloc((size_t)12*NN*sizeof(float));
  float* bsv   = (float*)alloc(128*sizeof(float));
  int*   segst = (int*)alloc((size_t)(BB+1)*sizeof(int));
  unsigned* bmax = (unsigned*)alloc((size_t)BB*sizeof(unsigned));
  float* pool  = (float*)alloc((size_t)BB*HH*sizeof(float));
  float* scrs  = (float*)alloc((size_t)NN*sizeof(float));
  size_t xpbRel = use6 ? 6 : 3;
  unsigned short* xpb = (unsigned short*)alloc((size_t)xpbRel*NN*128*sizeof(short));
  float* R1    = (float*)alloc((size_t)NN*128*sizeof(float));  // ebkt -> x0 -> hacc/h2
  float* R2    = (float*)alloc((size_t)NN*128*sizeof(float));  // h1 hi/lo

  unsigned* ebkt = (unsigned*)R1;        // NBK*CAP*4 = 38.4MB <= 51.2MB
  short* x0h = (short*)R1;
  short* x0l = x0h + (size_t)NN*32;
  float* hacc = R1;
  unsigned short* h1h = (unsigned short*)R2;
  unsigned short* h1l = h1h + (size_t)NN*128;
  float* h2 = use6 ? R1 : R2;            // path A: h2 aliases R2 (h1 dead); path B: R1
  unsigned short* aggH = (unsigned short*)xpb;          // [6][N][32]
  unsigned short* aggL = aggH + (size_t)RR*NN*32;
  float* zs = zsd;
  float* zd = zsd + (use6 ? (size_t)6*NN : (size_t)3*NN);

  // --- CSR build (no count pass: fixed-capacity staging) ---
  const int nch = (EE + CH - 1) / CH;
  hipMemsetAsync(bcur, 0, (size_t)NBK*sizeof(int), stream);
  k_binscatter<<<RR*nch,256,0,stream>>>(edges, bcur, ebkt);
  k_bscan<<<1,256,0,stream>>>(bcur, boff, off);
  k_bbuild<<<NBK,256,0,stream>>>(ebkt, bcur, boff, off, elist);

  // --- prep (featprep overwrites ebkt region AFTER bbuild) ---
  k_featprep<<<ceil_div(NN*32,256),256,0,stream>>>(x_all, pos_table, x0h, x0l);
  k_segbounds<<<ceil_div(BB+1,256),256,0,stream>>>(batch, segst, NN, BB);
  hipMemsetAsync(bmax, 0, (size_t)BB*sizeof(unsigned), stream);

  // --- layer 1: aggregate-then-project ---
  k_wa<32><<<ceil_div(12*32,256),256,0,stream>>>(W1, as1, ad1, 21, wa);
  k_zsd32<<<ceil_div(NN,256),256,0,stream>>>(x0h, x0l, wa, zsd, NN);
  k_wprep<32><<<ceil_div(RR*128*32,256),256,0,stream>>>(W1, 21, wtH, wtL);
  k_bsum<<<1,128,0,stream>>>(b1, bsv);
  k_agg1<<<ceil_div(NN*16,256),256,0,stream>>>((const unsigned short*)x0h, zsd, elist, off,
                                               aggH, aggL, NN);
  k_gemm1<<<ceil_div(NN,32),256,0,stream>>>((const short*)aggH, (const short*)aggL,
                                            wtH, wtL, bsv, n1w, n1b, h1h, h1l, NN);

  // --- layer 2 ---
  k_wprep<128><<<ceil_div(RR*128*128,256),256,0,stream>>>(W2, 128, wtH, wtL);
  k_bsum<<<1,128,0,stream>>>(b2, bsv);
  int aggGrid = ceil_div(NN*16, 256);
  if (use6) {
    dim3 g6(ceil_div(NN,32), 6);
    k_gemm_mfma<128><<<g6,256,0,stream>>>((const short*)h1h, (const short*)h1l,
                                          wtH, wtL, as2, ad2, xpb, zs, zd, 0, NN);
    k_agg3<6,3><<<aggGrid,256,0,stream>>>(xpb, zs, zd, elist, off, (float*)0,
        bsv, n2w, n2b, h2, query, batch, scrs, bmax, NN);
  } else {
    dim3 g3(ceil_div(NN,32), 3);
    k_gemm_mfma<128><<<g3,256,0,stream>>>((const short*)h1h, (const short*)h1l,
                                          wtH, wtL, as2, ad2, xpb, zs, zd, 0, NN);
    k_agg3<3,0><<<aggGrid,256,0,stream>>>(xpb, zs, zd, elist, off, hacc,
        bsv, n2w, n2b, (float*)0, query, batch, scrs, bmax, NN);
    k_gemm_mfma<128><<<g3,256,0,stream>>>((const short*)h1h, (const short*)h1l,
                                          wtH, wtL, as2, ad2, xpb, zs, zd, 3, NN);
    k_agg3<3,2><<<aggGrid,256,0,stream>>>(xpb, zs, zd, elist, off + (size_t)3*NN, hacc,
        bsv, n2w, n2b, h2, query, batch, scrs, bmax, NN);
  }

  // --- attention pooling ---
  k_pool<<<BB,128,0,stream>>>(h2, scrs, segst, bmax, pool, BB);
  k_outgemm<<<BB,128,0,stream>>>(pool, projW, projb, out, BB);
}

// Round 10
// 872.410 us; speedup vs baseline: 1.3956x; 1.0457x over previous
//
#include <hip/hip_runtime.h>
#include <math.h>

#define NN   100000
#define EE   800000
#define RR   6
#define BB   1000
#define HH   128
#define MM   (RR*NN)
#define NBPR ((NN + 255) >> 8)
#define NBK  (RR * NBPR)
#define CH   4096
#define CAP  4096     // fixed capacity per bucket in ebkt staging

static inline int ceil_div(int a, int b){ return (a+b-1)/b; }

typedef __attribute__((ext_vector_type(8))) short bf16x8;
typedef __attribute__((ext_vector_type(4))) short bf16x4;
typedef __attribute__((ext_vector_type(4))) float f32x4;

__device__ __forceinline__ unsigned fenc(float f){
  unsigned u = __float_as_uint(f);
  return (u & 0x80000000u) ? ~u : (u | 0x80000000u);
}
__device__ __forceinline__ float fdec(unsigned u){
  return __uint_as_float((u & 0x80000000u) ? (u & 0x7fffffffu) : ~u);
}
__device__ __forceinline__ unsigned short f2bf(float f){
  unsigned u = __float_as_uint(f);
  return (unsigned short)((u + 0x7fffu + ((u >> 16) & 1u)) >> 16);
}
__device__ __forceinline__ float bf2f(unsigned short h){
  return __uint_as_float(((unsigned)h) << 16);
}

// ================= CSR build: fixed-capacity binning (proven r9) =================
__global__ void k_binscatter(const int* __restrict__ edges, int* __restrict__ bcur,
                             unsigned* __restrict__ ebkt)
{
  __shared__ int hist[NBPR];
  __shared__ int base[NBPR];
  int t = threadIdx.x;
  const int nch = (EE + CH - 1) / CH;
  int r = blockIdx.x / nch, c = blockIdx.x - r*nch;
  for (int i = t; i < NBPR; i += 256) hist[i] = 0;
  __syncthreads();
  const int* sptr = edges + (size_t)r*2*EE;
  const int* dptr = sptr + EE;
  int e0 = c*CH, e1 = min(EE, e0 + CH);
  for (int i = e0 + t; i < e1; i += 256)
    atomicAdd(&hist[dptr[i] >> 8], 1);
  __syncthreads();
  for (int i = t; i < NBPR; i += 256) {
    int h = hist[i];
    int gb = r*NBPR + i;
    base[i] = h ? (gb*CAP + atomicAdd(&bcur[gb], h)) : 0;
    hist[i] = 0;
  }
  __syncthreads();
  for (int i = e0 + t; i < e1; i += 256) {
    int dst = dptr[i];
    int b = dst >> 8;
    int slot = base[b] + atomicAdd(&hist[b], 1);
    ebkt[slot] = ((unsigned)sptr[i] << 8) | (unsigned)(dst & 255);
  }
}

__global__ void k_bscan(const int* __restrict__ bcur, int* __restrict__ boff,
                        int* __restrict__ off)
{
  __shared__ int sh[256];
  int t = threadIdx.x;
  int carry = 0;
  for (int c = 0; c < NBK; c += 256) {
    int idx = c + t;
    int v = (idx < NBK) ? bcur[idx] : 0;
    sh[t] = v;
    __syncthreads();
    for (int o = 1; o < 256; o <<= 1) {
      int add = (t >= o) ? sh[t-o] : 0;
      __syncthreads();
      sh[t] += add;
      __syncthreads();
    }
    int incl = sh[t];
    int tot  = sh[255];
    if (idx < NBK) boff[idx] = carry + incl - v;
    __syncthreads();
    carry += tot;
  }
  if (t == 0) { boff[NBK] = carry; off[MM] = carry; }
}

__global__ void k_bbuild(const unsigned* __restrict__ ebkt, const int* __restrict__ bcur,
                         const int* __restrict__ boff,
                         int* __restrict__ off, int* __restrict__ elist)
{
  __shared__ int cnt[256];
  __shared__ int sc[256];
  __shared__ int cur[256];
  int t = threadIdx.x;
  int bb = blockIdx.x;
  int e0r = bb*CAP, e1r = e0r + bcur[bb];
  int w0 = boff[bb];
  cnt[t] = 0;
  __syncthreads();
  for (int i = e0r + t; i < e1r; i += 256)
    atomicAdd(&cnt[ebkt[i] & 255u], 1);
  __syncthreads();
  sc[t] = cnt[t];
  __syncthreads();
  for (int o = 1; o < 256; o <<= 1) {
    int add = (t >= o) ? sc[t-o] : 0;
    __syncthreads();
    sc[t] += add;
    __syncthreads();
  }
  int excl = sc[t] - cnt[t];
  int r = bb / NBPR, b = bb - r*NBPR;
  int dst = b*256 + t;
  if (dst < NN) off[r*NN + dst] = w0 + excl;
  cur[t] = w0 + excl;
  __syncthreads();
  for (int i = e0r + t; i < e1r; i += 256) {
    unsigned w = ebkt[i];
    int slot = atomicAdd(&cur[w & 255u], 1);
    elist[slot] = (int)(w >> 8);
  }
}

// ================= feature prep (bf16 hi/lo planes, K padded 21->32) =================
__global__ void k_featprep(const float* __restrict__ x_all, const float* __restrict__ pos_table,
                           short* __restrict__ x0h, short* __restrict__ x0l)
{
  int gid = blockIdx.x*256 + threadIdx.x;
  if (gid >= NN*32) return;
  int nidx = gid >> 5, c = gid & 31;
  float v = 0.f;
  if (c < 13) {
    int scl = (c < 5) ? c : c + 1;
    v = x_all[nidx*14 + scl];
  } else if (c < 21) {
    int pi = (int)x_all[nidx*14 + 5];
    pi = pi < 0 ? 0 : (pi > 23 ? 23 : pi);
    v = pos_table[pi*8 + (c - 13)];
  }
  unsigned short h = f2bf(v);
  unsigned short l = f2bf(v - bf2f(h));
  x0h[gid] = (short)h;
  x0l[gid] = (short)l;
}

// ================= weight prep =================
template<int KP>
__global__ void k_wprep(const float* __restrict__ W, int K,
                        short* __restrict__ Wh, short* __restrict__ Wl)
{
  int gid = blockIdx.x*256 + threadIdx.x;
  if (gid >= RR*128*KP) return;
  int r = gid / (128*KP);
  int rem = gid - r*(128*KP);
  int nn = rem / KP, k = rem - nn*KP;
  float v = (k < K) ? W[((size_t)r*K + k)*128 + nn] : 0.f;
  unsigned short h = f2bf(v);
  unsigned short l = f2bf(v - bf2f(h));
  Wh[gid] = (short)h;
  Wl[gid] = (short)l;
}

// ================= wa: precompute W_r @ a =================
template<int KP>
__global__ void k_wa(const float* __restrict__ W, const float* __restrict__ as,
                     const float* __restrict__ ad, int K, float* __restrict__ wa)
{
  int idx = blockIdx.x*256 + threadIdx.x;
  if (idx >= 12*KP) return;
  int rr = idx / KP, k = idx - rr*KP;
  int r = (rr < 6) ? rr : rr - 6;
  const float* a = ((rr < 6) ? as : ad) + (size_t)r*HH;
  float s = 0.f;
  if (k < K) {
    const float* wrow = W + ((size_t)r*K + k)*128;
    #pragma unroll 8
    for (int h = 0; h < 128; ++h) s = fmaf(wrow[h], a[h], s);
  }
  wa[idx] = s;
}

// ================= zsd: layer-1 z-scores [12][N] =================
__global__ void k_zsd32(const short* __restrict__ xh, const short* __restrict__ xl,
                        const float* __restrict__ wa, float* __restrict__ zsd, int n)
{
  __shared__ float w[12*32];
  int tid = threadIdx.x;
  for (int i = tid; i < 12*32; i += 256) w[i] = wa[i];
  __syncthreads();
  int g = blockIdx.x*256 + tid;
  if (g >= n) return;
  float v[32];
  #pragma unroll
  for (int c = 0; c < 4; ++c) {
    uint4 vh = *(const uint4*)(xh + (size_t)g*32 + c*8);
    uint4 vl = *(const uint4*)(xl + (size_t)g*32 + c*8);
    const unsigned short* hp = (const unsigned short*)&vh;
    const unsigned short* lp = (const unsigned short*)&vl;
    #pragma unroll
    for (int j = 0; j < 8; ++j) v[c*8+j] = bf2f(hp[j]) + bf2f(lp[j]);
  }
  #pragma unroll
  for (int rr = 0; rr < 12; ++rr) {
    float d = 0.f;
    #pragma unroll
    for (int k = 0; k < 32; ++k) d = fmaf(v[k], w[rr*32+k], d);
    zsd[(size_t)rr*n + g] = d;
  }
}

// ================= layer-1 aggregation (2-deep pipelined gather) =================
__global__ void k_agg1(const unsigned short* __restrict__ x0h, const float* __restrict__ zsd,
                       const int* __restrict__ elist, const int* __restrict__ off,
                       unsigned short* __restrict__ aggH, unsigned short* __restrict__ aggL,
                       int n)
{
  int gid = blockIdx.x*256 + threadIdx.x;
  int g = gid >> 4;
  int l = threadIdx.x & 15;
  if (g >= n) return;
  int sub = l >> 2, ch = l & 3;

  for (int rel = 0; rel < RR; ++rel) {
    const float* zsr = zsd + (size_t)rel*n;
    const float* zdr = zsd + (size_t)(6+rel)*n;
    int o0 = off[(size_t)rel*NN + g];
    int deg = off[(size_t)rel*NN + g + 1] - o0;
    float acc[8] = {0,0,0,0,0,0,0,0};
    float inv = 0.f;
    if (deg > 0) {
      float zdd = zdr[g];
      float m = -3.4e38f, es = 0.f;
      for (int i = l; i < deg; i += 16) {
        float z = zsr[elist[o0+i]] + zdd;
        z = (z > 0.f) ? z : 0.2f*z;
        float mn = fmaxf(m, z);
        es = es*__expf(m - mn) + __expf(z - mn);
        m = mn;
      }
      #pragma unroll
      for (int o = 1; o <= 8; o <<= 1) {
        float mo = __shfl_xor(m, o), eo = __shfl_xor(es, o);
        float mn = fmaxf(m, mo);
        es = es*__expf(m - mn) + eo*__expf(mo - mn);
        m = mn;
      }
      inv = 1.f / es;
      for (int base = 0; base < deg; base += 8) {
        int i0 = base + sub, i1 = base + 4 + sub;
        float e0 = 0.f, e1 = 0.f; int s0 = 0, s1 = 0;
        if (i0 < deg) {
          s0 = elist[o0+i0];
          float z = zsr[s0] + zdd;
          z = (z > 0.f) ? z : 0.2f*z;
          e0 = __expf(z - m);
        }
        if (i1 < deg) {
          s1 = elist[o0+i1];
          float z = zsr[s1] + zdd;
          z = (z > 0.f) ? z : 0.2f*z;
          e1 = __expf(z - m);
        }
        uint4 v0 = *(const uint4*)(x0h + (size_t)s0*32 + ch*8);
        uint4 v1 = *(const uint4*)(x0h + (size_t)s1*32 + ch*8);
        acc[0] = fmaf(e0, __uint_as_float(v0.x << 16),         acc[0]);
        acc[1] = fmaf(e0, __uint_as_float(v0.x & 0xffff0000u), acc[1]);
        acc[2] = fmaf(e0, __uint_as_float(v0.y << 16),         acc[2]);
        acc[3] = fmaf(e0, __uint_as_float(v0.y & 0xffff0000u), acc[3]);
        acc[4] = fmaf(e0, __uint_as_float(v0.z << 16),         acc[4]);
        acc[5] = fmaf(e0, __uint_as_float(v0.z & 0xffff0000u), acc[5]);
        acc[6] = fmaf(e0, __uint_as_float(v0.w << 16),         acc[6]);
        acc[7] = fmaf(e0, __uint_as_float(v0.w & 0xffff0000u), acc[7]);
        acc[0] = fmaf(e1, __uint_as_float(v1.x << 16),         acc[0]);
        acc[1] = fmaf(e1, __uint_as_float(v1.x & 0xffff0000u), acc[1]);
        acc[2] = fmaf(e1, __uint_as_float(v1.y << 16),         acc[2]);
        acc[3] = fmaf(e1, __uint_as_float(v1.y & 0xffff0000u), acc[3]);
        acc[4] = fmaf(e1, __uint_as_float(v1.z << 16),         acc[4]);
        acc[5] = fmaf(e1, __uint_as_float(v1.z & 0xffff0000u), acc[5]);
        acc[6] = fmaf(e1, __uint_as_float(v1.w << 16),         acc[6]);
        acc[7] = fmaf(e1, __uint_as_float(v1.w & 0xffff0000u), acc[7]);
      }
      #pragma unroll
      for (int j = 0; j < 8; ++j) {
        acc[j] += __shfl_xor(acc[j], 4);
        acc[j] += __shfl_xor(acc[j], 8);
      }
    }
    if (sub == 0) {
      uint4 ph, pl;
      unsigned* php = (unsigned*)&ph; unsigned* plp = (unsigned*)&pl;
      #pragma unroll
      for (int j2 = 0; j2 < 4; ++j2) {
        float a0 = acc[2*j2]   * inv;
        float a1 = acc[2*j2+1] * inv;
        unsigned short h0 = f2bf(a0), h1 = f2bf(a1);
        php[j2] = ((unsigned)h1 << 16) | h0;
        plp[j2] = ((unsigned)f2bf(a1 - bf2f(h1)) << 16) | f2bf(a0 - bf2f(h0));
      }
      size_t o = ((size_t)rel*n + g)*32 + ch*8;
      *(uint4*)(aggH + o) = ph;
      *(uint4*)(aggL + o) = pl;
    }
  }
}

// ================= layer-1 concat-GEMM; h1 output bf16-only =================
__device__ __forceinline__ bf16x8 ldfragG(const short* __restrict__ p, int row, int kb, int KP_)
{
  bf16x4 a = *(const bf16x4*)(p + (size_t)row*KP_ + kb);
  bf16x4 b = *(const bf16x4*)(p + (size_t)row*KP_ + kb + 16);
  return __builtin_shufflevector(a, b, 0,1,2,3,4,5,6,7);
}

__global__ __launch_bounds__(256, 4)
void k_gemm1(const short* __restrict__ aggH, const short* __restrict__ aggL,
             const short* __restrict__ Wh, const short* __restrict__ Wl,
             const float* __restrict__ bsv,
             const float* __restrict__ nw, const float* __restrict__ nb,
             unsigned short* __restrict__ Yh, int n)
{
  __shared__ __align__(16) float Cs[32*136];
  int tid = threadIdx.x;
  int r0 = blockIdx.x * 32;
  int wid = tid >> 6, lane = tid & 63;
  int lr = lane & 15, lg = lane >> 4;
  int rt = wid >> 1;
  int c0 = (wid & 1) * 4;
  int arow = r0 + rt*16 + lr;
  int kb = 4*lg;
  f32x4 acct[4] = {{0,0,0,0},{0,0,0,0},{0,0,0,0},{0,0,0,0}};

  for (int rel = 0; rel < RR; ++rel) {
    const short* Ahr = aggH + (size_t)rel*n*32;
    const short* Alr = aggL + (size_t)rel*n*32;
    const short* Whr = Wh + (size_t)rel*128*32;
    const short* Wlr = Wl + (size_t)rel*128*32;
    bf16x8 ah = ldfragG(Ahr, arow, kb, 32);
    bf16x8 al = ldfragG(Alr, arow, kb, 32);
    #pragma unroll
    for (int t = 0; t < 4; ++t) {
      int wrow = (c0 + t)*16 + lr;
      bf16x8 whf = ldfragG(Whr, wrow, kb, 32);
      bf16x8 wlf = ldfragG(Wlr, wrow, kb, 32);
      acct[t] = __builtin_amdgcn_mfma_f32_16x16x32_bf16(ah, whf, acct[t], 0, 0, 0);
      acct[t] = __builtin_amdgcn_mfma_f32_16x16x32_bf16(al, whf, acct[t], 0, 0, 0);
      acct[t] = __builtin_amdgcn_mfma_f32_16x16x32_bf16(ah, wlf, acct[t], 0, 0, 0);
    }
  }

  #pragma unroll
  for (int t = 0; t < 4; ++t)
    #pragma unroll
    for (int v = 0; v < 4; ++v) {
      int row = rt*16 + lg*4 + v;
      int col = (c0 + t)*16 + lr;
      float x = acct[t][v] + bsv[col];
      Cs[row*136 + col] = 0.5f*x*(1.f + erff(x*0.70710678118654752f));
    }
  __syncthreads();
  {
    int r = tid >> 3, sg = tid & 7;
    float vals[16];
    float s = 0.f;
    #pragma unroll
    for (int i = 0; i < 16; ++i) { vals[i] = Cs[r*136 + sg*16 + i]; s += vals[i]; }
    s += __shfl_xor(s, 1); s += __shfl_xor(s, 2); s += __shfl_xor(s, 4);
    float mu = s * (1.f/128.f);
    float var = 0.f;
    #pragma unroll
    for (int i = 0; i < 16; ++i) { vals[i] -= mu; var += vals[i]*vals[i]; }
    var += __shfl_xor(var, 1); var += __shfl_xor(var, 2); var += __shfl_xor(var, 4);
    float inv = 1.f / sqrtf(var*(1.f/128.f) + 1e-5f);
    int g = r0 + r;
    uint4 ph0, ph1;
    unsigned* php0 = (unsigned*)&ph0; unsigned* php1 = (unsigned*)&ph1;
    #pragma unroll
    for (int j2 = 0; j2 < 8; ++j2) {
      int c = sg*16 + 2*j2;
      float y0 = vals[2*j2]  *inv*nw[c]   + nb[c];
      float y1 = vals[2*j2+1]*inv*nw[c+1] + nb[c+1];
      unsigned hw = ((unsigned)f2bf(y1) << 16) | f2bf(y0);
      if (j2 < 4) php0[j2] = hw; else php1[j2-4] = hw;
    }
    *(uint4*)(Yh + (size_t)g*128 + sg*16)     = ph0;
    *(uint4*)(Yh + (size_t)g*128 + sg*16 + 8) = ph1;
  }
}

// ================= layer-2 MFMA GEMM (A bf16-only; 2-term hi/lo W) ========
__device__ __forceinline__ bf16x8 ldfrag_(const short* p, int row, int kb, int KP_, int smask)
{
  int xr = row & smask;
  int s0 = (((kb)      >> 3) ^ xr) * 8 + (kb & 7);
  int s1 = (((kb + 16) >> 3) ^ xr) * 8 + (kb & 7);
  bf16x4 a = *(const bf16x4*)(p + (size_t)row*KP_ + s0);
  bf16x4 b = *(const bf16x4*)(p + (size_t)row*KP_ + s1);
  return __builtin_shufflevector(a, b, 0,1,2,3,4,5,6,7);
}

template<int KP>
__global__ __launch_bounds__(256, 2)
void k_gemm_mfma(const short* __restrict__ Ah,
                 const short* __restrict__ WhAll, const short* __restrict__ WlAll,
                 const float* __restrict__ a_sAll, const float* __restrict__ a_dAll,
                 unsigned short* __restrict__ xpbAll, float* __restrict__ zsAll,
                 float* __restrict__ zdAll, int rbase, int n)
{
  constexpr int SLOTS = KP/8;
  constexpr int SMASK = (SLOTS >= 8) ? 7 : (SLOTS-1);
  __shared__ short lds[288*KP];
  constexpr int AH0 = 0, WH0 = 32*KP, WL0 = 160*KP;
  int tid = threadIdx.x;
  int r0 = blockIdx.x * 32;
  int ry = blockIdx.y;
  const short* Wh = WhAll + (size_t)(rbase+ry)*128*KP;
  const short* Wl = WlAll + (size_t)(rbase+ry)*128*KP;
  const float* a_s = a_sAll + (size_t)(rbase+ry)*HH;
  const float* a_d = a_dAll + (size_t)(rbase+ry)*HH;
  unsigned short* xpb = xpbAll + (size_t)ry*n*128;
  float* zs = zsAll + (size_t)ry*n;
  float* zd = zdAll + (size_t)ry*n;

  for (int ch = tid; ch < 32*SLOTS; ch += 256) {
    int row = ch / SLOTS, slot = ch - row*SLOTS;
    int gr = r0 + row;
    int dsl = (slot ^ (row & SMASK)) * 8;
    bf16x8 vh;
    if (gr < n) {
      vh = *(const bf16x8*)(Ah + (size_t)gr*KP + slot*8);
    } else {
      #pragma unroll
      for (int q = 0; q < 8; ++q) vh[q] = 0;
    }
    *(bf16x8*)(lds + AH0 + row*KP + dsl) = vh;
  }
  for (int ch = tid; ch < 128*SLOTS; ch += 256) {
    int row = ch / SLOTS, slot = ch - row*SLOTS;
    int dsl = (slot ^ (row & SMASK)) * 8;
    *(bf16x8*)(lds + WH0 + row*KP + dsl) = *(const bf16x8*)(Wh + (size_t)row*KP + slot*8);
    *(bf16x8*)(lds + WL0 + row*KP + dsl) = *(const bf16x8*)(Wl + (size_t)row*KP + slot*8);
  }
  __syncthreads();

  int wid = tid >> 6, lane = tid & 63;
  int lr = lane & 15, lg = lane >> 4;
  int rt = wid >> 1;
  int c0 = (wid & 1) * 4;
  f32x4 acc[4] = {{0,0,0,0},{0,0,0,0},{0,0,0,0},{0,0,0,0}};
  int arow = rt*16 + lr;

  #pragma unroll
  for (int kc = 0; kc < KP/32; ++kc) {
    int kb = kc*32 + 4*lg;
    bf16x8 ah = ldfrag_(lds + AH0, arow, kb, KP, SMASK);
    #pragma unroll
    for (int t = 0; t < 4; ++t) {
      int wrow = (c0 + t)*16 + lr;
      bf16x8 wh = ldfrag_(lds + WH0, wrow, kb, KP, SMASK);
      bf16x8 wl = ldfrag_(lds + WL0, wrow, kb, KP, SMASK);
      acc[t] = __builtin_amdgcn_mfma_f32_16x16x32_bf16(ah, wh, acc[t], 0, 0, 0);
      acc[t] = __builtin_amdgcn_mfma_f32_16x16x32_bf16(ah, wl, acc[t], 0, 0, 0);
    }
  }
  __syncthreads();

  float* Cs = (float*)lds;   // [32][136]
  #pragma unroll
  for (int t = 0; t < 4; ++t)
    #pragma unroll
    for (int v = 0; v < 4; ++v) {
      int row = rt*16 + lg*4 + v;
      int col = (c0 + t)*16 + lr;
      Cs[row*136 + col] = acc[t][v];
    }
  __syncthreads();

  {
    int r = tid >> 3, sg = tid & 7;
    float ps = 0.f, pd = 0.f;
    #pragma unroll
    for (int i = 0; i < 16; ++i) {
      int c = sg*16 + i;
      float x = Cs[r*136 + c];
      ps = fmaf(x, a_s[c], ps);
      pd = fmaf(x, a_d[c], pd);
    }
    ps += __shfl_xor(ps, 1); pd += __shfl_xor(pd, 1);
    ps += __shfl_xor(ps, 2); pd += __shfl_xor(pd, 2);
    ps += __shfl_xor(ps, 4); pd += __shfl_xor(pd, 4);
    int gr = r0 + r;
    if (sg == 0 && gr < n) { zs[gr] = ps; zd[gr] = pd; }
  }
  for (int i = tid; i < 32*16; i += 256) {
    int row = i >> 4, q = i & 15;
    int gr = r0 + row;
    if (gr < n) {
      const float* cp = Cs + row*136 + q*8;
      uint4 o;
      o.x = ((unsigned)f2bf(cp[1]) << 16) | f2bf(cp[0]);
      o.y = ((unsigned)f2bf(cp[3]) << 16) | f2bf(cp[2]);
      o.z = ((unsigned)f2bf(cp[5]) << 16) | f2bf(cp[4]);
      o.w = ((unsigned)f2bf(cp[7]) << 16) | f2bf(cp[6]);
      *(uint4*)(xpb + (size_t)gr*128 + q*8) = o;
    }
  }
}

// ================= layer-2 mega-agg (4-deep pipelined gather) =================
#define ACC8(W_, U_) \
  tmp[0] = fmaf(W_, __uint_as_float((U_).x << 16),         tmp[0]); \
  tmp[1] = fmaf(W_, __uint_as_float((U_).x & 0xffff0000u), tmp[1]); \
  tmp[2] = fmaf(W_, __uint_as_float((U_).y << 16),         tmp[2]); \
  tmp[3] = fmaf(W_, __uint_as_float((U_).y & 0xffff0000u), tmp[3]); \
  tmp[4] = fmaf(W_, __uint_as_float((U_).z << 16),         tmp[4]); \
  tmp[5] = fmaf(W_, __uint_as_float((U_).z & 0xffff0000u), tmp[5]); \
  tmp[6] = fmaf(W_, __uint_as_float((U_).w << 16),         tmp[6]); \
  tmp[7] = fmaf(W_, __uint_as_float((U_).w & 0xffff0000u), tmp[7]);

// FIN=0: write hacc. FIN=2: +hacc+bias finalize. FIN=3: +bias finalize (no hacc).
template<int NREL, int FIN>
__global__ void k_agg3(const unsigned short* __restrict__ xpb,  // [NREL][n][128]
                       const float* __restrict__ zs,            // [NREL][n]
                       const float* __restrict__ zd,
                       const int* __restrict__ elist,
                       const int* __restrict__ off,
                       float* __restrict__ hacc,
                       const float* __restrict__ bsum,
                       const float* __restrict__ nw, const float* __restrict__ nb,
                       float* __restrict__ Yf,
                       const float* __restrict__ q,
                       const int* __restrict__ batch,
                       float* __restrict__ scores, unsigned* __restrict__ bmax,
                       int n)
{
  int gid = blockIdx.x*256 + threadIdx.x;
  int g = gid >> 4;
  int l = threadIdx.x & 15;
  int gbase = threadIdx.x & 48;
  if (g >= n) return;

  float acc[8] = {0,0,0,0,0,0,0,0};

  for (int r = 0; r < NREL; ++r) {
    int o0 = off[(size_t)r*NN + g], o1 = off[(size_t)r*NN + g + 1];
    int deg = o1 - o0;
    if (deg <= 0) continue;
    const float* zsr = zs + (size_t)r*n;
    float zdd = zd[(size_t)r*n + g];

    float m = -3.4e38f;
    for (int i = l; i < deg; i += 16) {
      float z = zsr[elist[o0+i]] + zdd;
      z = (z > 0.f) ? z : 0.2f*z;
      m = fmaxf(m, z);
    }
    m = fmaxf(m, __shfl_xor(m, 1));
    m = fmaxf(m, __shfl_xor(m, 2));
    m = fmaxf(m, __shfl_xor(m, 4));
    m = fmaxf(m, __shfl_xor(m, 8));

    float tmp[8] = {0,0,0,0,0,0,0,0};
    float esum = 0.f;
    const unsigned short* xr = xpb + (size_t)r*n*128;
    for (int base = 0; base < deg; base += 16) {
      int i = base + l;
      float ew = 0.f; int s = 0;
      if (i < deg) {
        s = elist[o0+i];
        float z = zsr[s] + zdd;
        z = (z > 0.f) ? z : 0.2f*z;
        ew = __expf(z - m);
      }
      esum += ew;
      int cnt = min(16, deg - base);
      for (int t = 0; t < cnt; t += 4) {
        float w0 = __shfl(ew, gbase + t);
        float w1 = __shfl(ew, gbase + t + 1);
        float w2 = __shfl(ew, gbase + t + 2);
        float w3 = __shfl(ew, gbase + t + 3);
        int a0 = __shfl(s, gbase + t);
        int a1 = __shfl(s, gbase + t + 1);
        int a2 = __shfl(s, gbase + t + 2);
        int a3 = __shfl(s, gbase + t + 3);
        uint4 u0 = *(const uint4*)(xr + (size_t)a0*128 + l*8);
        uint4 u1 = *(const uint4*)(xr + (size_t)a1*128 + l*8);
        uint4 u2 = *(const uint4*)(xr + (size_t)a2*128 + l*8);
        uint4 u3 = *(const uint4*)(xr + (size_t)a3*128 + l*8);
        ACC8(w0, u0);
        ACC8(w1, u1);
        ACC8(w2, u2);
        ACC8(w3, u3);
      }
    }
    esum += __shfl_xor(esum, 1);
    esum += __shfl_xor(esum, 2);
    esum += __shfl_xor(esum, 4);
    esum += __shfl_xor(esum, 8);
    float inv = 1.f / esum;
    #pragma unroll
    for (int j = 0; j < 8; ++j) acc[j] = fmaf(tmp[j], inv, acc[j]);
  }

  if (FIN == 0) {
    float* hp = hacc + (size_t)g*128 + l*8;
    float4 o0; o0.x = acc[0]; o0.y = acc[1]; o0.z = acc[2]; o0.w = acc[3];
    float4 o1; o1.x = acc[4]; o1.y = acc[5]; o1.z = acc[6]; o1.w = acc[7];
    *(float4*)hp = o0;
    *(float4*)(hp + 4) = o1;
  } else {
    if (FIN == 2) {
      const float* hp = hacc + (size_t)g*128 + l*8;
      float4 p0 = *(const float4*)hp;
      float4 p1 = *(const float4*)(hp + 4);
      acc[0] += p0.x; acc[1] += p0.y; acc[2] += p0.z; acc[3] += p0.w;
      acc[4] += p1.x; acc[5] += p1.y; acc[6] += p1.z; acc[7] += p1.w;
    }
    float4 b0 = *(const float4*)(bsum + l*8);
    float4 b1 = *(const float4*)(bsum + l*8 + 4);
    acc[0] += b0.x; acc[1] += b0.y; acc[2] += b0.z; acc[3] += b0.w;
    acc[4] += b1.x; acc[5] += b1.y; acc[6] += b1.z; acc[7] += b1.w;
    float s = 0.f;
    #pragma unroll
    for (int j = 0; j < 8; ++j) {
      acc[j] = 0.5f*acc[j]*(1.f + erff(acc[j]*0.70710678118654752f));
      s += acc[j];
    }
    s += __shfl_xor(s, 1); s += __shfl_xor(s, 2);
    s += __shfl_xor(s, 4); s += __shfl_xor(s, 8);
    float mu = s * (1.f/128.f);
    float v = 0.f;
    #pragma unroll
    for (int j = 0; j < 8; ++j) { acc[j] -= mu; v += acc[j]*acc[j]; }
    v += __shfl_xor(v, 1); v += __shfl_xor(v, 2);
    v += __shfl_xor(v, 4); v += __shfl_xor(v, 8);
    v *= (1.f/128.f);
    float inv = 1.f / sqrtf(v + 1e-5f);
    float4 w0 = *(const float4*)(nw + l*8);
    float4 w1 = *(const float4*)(nw + l*8 + 4);
    float4 nb0 = *(const float4*)(nb + l*8);
    float4 nb1 = *(const float4*)(nb + l*8 + 4);
    float y[8];
    y[0] = acc[0]*inv*w0.x + nb0.x; y[1] = acc[1]*inv*w0.y + nb0.y;
    y[2] = acc[2]*inv*w0.z + nb0.z; y[3] = acc[3]*inv*w0.w + nb0.w;
    y[4] = acc[4]*inv*w1.x + nb1.x; y[5] = acc[5]*inv*w1.y + nb1.y;
    y[6] = acc[6]*inv*w1.z + nb1.z; y[7] = acc[7]*inv*w1.w + nb1.w;
    float* yp = Yf + (size_t)g*128 + l*8;
    float4 o0; o0.x = y[0]; o0.y = y[1]; o0.z = y[2]; o0.w = y[3];
    float4 o1; o1.x = y[4]; o1.y = y[5]; o1.z = y[6]; o1.w = y[7];
    *(float4*)yp = o0;
    *(float4*)(yp + 4) = o1;
    float4 q0 = *(const float4*)(q + l*8);
    float4 q1 = *(const float4*)(q + l*8 + 4);
    float sc = y[0]*q0.x + y[1]*q0.y + y[2]*q0.z + y[3]*q0.w
             + y[4]*q1.x + y[5]*q1.y + y[6]*q1.z + y[7]*q1.w;
    sc += __shfl_xor(sc, 1); sc += __shfl_xor(sc, 2);
    sc += __shfl_xor(sc, 4); sc += __shfl_xor(sc, 8);
    if (l == 0) {
      scores[g] = sc;
      atomicMax(&bmax[batch[g]], fenc(sc));
    }
  }
}

// ================= bias-sum =================
__global__ void k_bsum(const float* __restrict__ b, float* __restrict__ bs)
{
  int t = threadIdx.x;
  float s = 0.f;
  #pragma unroll
  for (int r = 0; r < RR; ++r) s += b[r*HH + t];
  bs[t] = s;
}

// ================= pooling =================
__global__ void k_segbounds(const int* __restrict__ batch, int* __restrict__ segst,
                            int n, int numB)
{
  int b = blockIdx.x*256 + threadIdx.x;
  if (b > numB) return;
  int lo = 0, hi = n;
  while (lo < hi) { int mid = (lo+hi) >> 1; if (batch[mid] < b) lo = mid+1; else hi = mid; }
  segst[b] = lo;
}

__global__ void k_pool(const float* __restrict__ X, const float* __restrict__ scores,
                       const int* __restrict__ segst, const unsigned* __restrict__ bmax,
                       float* __restrict__ pool, int numB)
{
  int b = blockIdx.x;
  int t = threadIdx.x;
  int s0 = segst[b], s1 = segst[b+1];
  float m = fdec(bmax[b]);
  float acc0 = 0.f, acc1 = 0.f, esum = 0.f;
  int i = s0;
  for (; i + 1 < s1; i += 2) {
    float e0 = __expf(scores[i] - m);
    float e1 = __expf(scores[i+1] - m);
    esum += e0 + e1;
    acc0 = fmaf(e0, X[(size_t)i*128 + t], acc0);
    acc1 = fmaf(e1, X[(size_t)(i+1)*128 + t], acc1);
  }
  if (i < s1) {
    float e0 = __expf(scores[i] - m);
    esum += e0;
    acc0 = fmaf(e0, X[(size_t)i*128 + t], acc0);
  }
  float inv = (s1 > s0) ? 1.f/esum : 0.f;
  pool[(size_t)b*128 + t] = (acc0 + acc1) * inv;
}

__global__ void k_outgemm(const float* __restrict__ pool, const float* __restrict__ projW,
                          const float* __restrict__ projb, float* __restrict__ out, int numB)
{
  int b = blockIdx.x;
  int j = threadIdx.x;
  __shared__ float p[128];
  p[j] = pool[(size_t)b*128 + j];
  __syncthreads();
  float acc = projb[j];
  #pragma unroll 16
  for (int k = 0; k < 128; ++k) acc = fmaf(p[k], projW[(size_t)k*128 + j], acc);
  out[(size_t)b*128 + j] = acc;
}

// ================= launcher =================
extern "C" void kernel_launch(void* const* d_in, const int* in_sizes, int n_in,
                              void* d_out, int out_size, void* d_ws, size_t ws_size,
                              hipStream_t stream)
{
  const float* x_all = (const float*)d_in[0];
  const int*   edges = (const int*)d_in[1];
  const int*   batch = (const int*)d_in[2];
  const float* pos_table = (const float*)d_in[3];
  const float* W1  = (const float*)d_in[4];
  const float* as1 = (const float*)d_in[5];
  const float* ad1 = (const float*)d_in[6];
  const float* b1  = (const float*)d_in[7];
  const float* W2  = (const float*)d_in[8];
  const float* as2 = (const float*)d_in[9];
  const float* ad2 = (const float*)d_in[10];
  const float* b2  = (const float*)d_in[11];
  const float* n1w = (const float*)d_in[12];
  const float* n1b = (const float*)d_in[13];
  const float* n2w = (const float*)d_in[14];
  const float* n2b = (const float*)d_in[15];
  const float* query = (const float*)d_in[16];
  const float* projW = (const float*)d_in[17];
  const float* projb = (const float*)d_in[18];
  float* out = (float*)d_out;
  (void)in_sizes; (void)n_in; (void)out_size;

  auto asz = [](size_t b){ return (b + 255) & ~(size_t)255; };
  size_t baseNeed =
      asz((size_t)(MM+1)*4) + asz((size_t)RR*EE*4) + asz((size_t)(NBK+1)*4) +
      asz((size_t)NBK*4) + 2*asz((size_t)RR*128*128*2) + asz((size_t)12*128*4) +
      asz((size_t)12*NN*4) + asz(128*4) + asz((size_t)(BB+1)*4) + asz((size_t)BB*4) +
      asz((size_t)BB*HH*4) + asz((size_t)NN*4) +
      asz((size_t)NN*128*4) /*R1*/ + asz((size_t)NN*128*4) /*R2*/;
  size_t need6 = baseNeed + asz((size_t)6*NN*128*2);
  const bool use6 = ws_size >= need6;

  char* p = (char*)d_ws;
  auto alloc = [&](size_t b){ void* r = (void*)p; p += (b + 255) & ~(size_t)255; return r; };
  int*   off   = (int*)alloc((size_t)(MM+1)*sizeof(int));
  int*   elist = (int*)alloc((size_t)RR*EE*sizeof(int));
  int*   boff  = (int*)alloc((size_t)(NBK+1)*sizeof(int));
  int*   bcur  = (int*)alloc((size_t)NBK*sizeof(int));
  short* wtH   = (short*)alloc((size_t)RR*128*128*sizeof(short));
  short* wtL   = (short*)alloc((size_t)RR*128*128*sizeof(short));
  float* wa    = (float*)alloc((size_t)12*128*sizeof(float));
  float* zsd   = (float*)alloc((size_t)12*NN*sizeof(float));
  float* bsv   = (float*)alloc(128*sizeof(float));
  int*   segst = (int*)alloc((size_t)(BB+1)*sizeof(int));
  unsigned* bmax = (unsigned*)alloc((size_t)BB*sizeof(unsigned));
  float* pool  = (float*)alloc((size_t)BB*HH*sizeof(float));
  float* scrs  = (float*)alloc((size_t)NN*sizeof(float));
  size_t xpbRel = use6 ? 6 : 3;
  unsigned short* xpb = (unsigned short*)alloc((size_t)xpbRel*NN*128*sizeof(short));
  float* R1    = (float*)alloc((size_t)NN*128*sizeof(float));  // ebkt -> x0 -> hacc
  float* R2    = (float*)alloc((size_t)NN*128*sizeof(float));  // h1h (bf16) -> h2 (f32)

  unsigned* ebkt = (unsigned*)R1;        // NBK*CAP*4 = 38.4MB <= 51.2MB
  short* x0h = (short*)R1;
  short* x0l = x0h + (size_t)NN*32;
  float* hacc = R1;
  unsigned short* h1h = (unsigned short*)R2;   // [N][128] bf16 (front 25.6MB of R2)
  float* h2 = (float*)R2;                      // f32, written after h1h is dead
  unsigned short* aggH = (unsigned short*)xpb; // [6][N][32]
  unsigned short* aggL = aggH + (size_t)RR*NN*32;
  float* zs = zsd;
  float* zd = zsd + (use6 ? (size_t)6*NN : (size_t)3*NN);

  // --- CSR build (fixed-capacity staging, no count pass) ---
  const int nch = (EE + CH - 1) / CH;
  hipMemsetAsync(bcur, 0, (size_t)NBK*sizeof(int), stream);
  k_binscatter<<<RR*nch,256,0,stream>>>(edges, bcur, ebkt);
  k_bscan<<<1,256,0,stream>>>(bcur, boff, off);
  k_bbuild<<<NBK,256,0,stream>>>(ebkt, bcur, boff, off, elist);

  // --- prep (featprep overwrites ebkt region AFTER bbuild) ---
  k_featprep<<<ceil_div(NN*32,256),256,0,stream>>>(x_all, pos_table, x0h, x0l);
  k_segbounds<<<ceil_div(BB+1,256),256,0,stream>>>(batch, segst, NN, BB);
  hipMemsetAsync(bmax, 0, (size_t)BB*sizeof(unsigned), stream);

  // --- layer 1: aggregate-then-project ---
  k_wa<32><<<ceil_div(12*32,256),256,0,stream>>>(W1, as1, ad1, 21, wa);
  k_zsd32<<<ceil_div(NN,256),256,0,stream>>>(x0h, x0l, wa, zsd, NN);
  k_wprep<32><<<ceil_div(RR*128*32,256),256,0,stream>>>(W1, 21, wtH, wtL);
  k_bsum<<<1,128,0,stream>>>(b1, bsv);
  k_agg1<<<ceil_div(NN*16,256),256,0,stream>>>((const unsigned short*)x0h, zsd, elist, off,
                                               aggH, aggL, NN);
  k_gemm1<<<ceil_div(NN,32),256,0,stream>>>((const short*)aggH, (const short*)aggL,
                                            wtH, wtL, bsv, n1w, n1b, h1h, NN);

  // --- layer 2 ---
  k_wprep<128><<<ceil_div(RR*128*128,256),256,0,stream>>>(W2, 128, wtH, wtL);
  k_bsum<<<1,128,0,stream>>>(b2, bsv);
  int aggGrid = ceil_div(NN*16, 256);
  if (use6) {
    dim3 g6(ceil_div(NN,32), 6);
    k_gemm_mfma<128><<<g6,256,0,stream>>>((const short*)h1h,
                                          wtH, wtL, as2, ad2, xpb, zs, zd, 0, NN);
    k_agg3<6,3><<<aggGrid,256,0,stream>>>(xpb, zs, zd, elist, off, (float*)0,
        bsv, n2w, n2b, h2, query, batch, scrs, bmax, NN);
  } else {
    dim3 g3(ceil_div(NN,32), 3);
    k_gemm_mfma<128><<<g3,256,0,stream>>>((const short*)h1h,
                                          wtH, wtL, as2, ad2, xpb, zs, zd, 0, NN);
    k_agg3<3,0><<<aggGrid,256,0,stream>>>(xpb, zs, zd, elist, off, hacc,
        bsv, n2w, n2b, (float*)0, query, batch, scrs, bmax, NN);
    k_gemm_mfma<128><<<g3,256,0,stream>>>((const short*)h1h,
                                          wtH, wtL, as2, ad2, xpb, zs, zd, 3, NN);
    k_agg3<3,2><<<aggGrid,256,0,stream>>>(xpb, zs, zd, elist, off + (size_t)3*NN, hacc,
        bsv, n2w, n2b, h2, query, batch, scrs, bmax, NN);
  }

  // --- attention pooling ---
  k_pool<<<BB,128,0,stream>>>(h2, scrs, segst, bmax, pool, BB);
  k_outgemm<<<BB,128,0,stream>>>(pool, projW, projb, out, BB);
}